// Round 12
// baseline (87.153 us; speedup 1.0000x reference)
//
#include <hip/hip_runtime.h>
#include <stdint.h>

typedef __bf16 bf16x8 __attribute__((ext_vector_type(8)));
typedef float f32x4 __attribute__((ext_vector_type(4)));
typedef unsigned short u16x4 __attribute__((ext_vector_type(4)));
typedef unsigned short u16x8 __attribute__((ext_vector_type(8)));

#define MFMA16(a, b, c) __builtin_amdgcn_mfma_f32_16x16x32_bf16(a, b, c, 0, 0, 0)

__device__ __forceinline__ unsigned short f2bf(float f) {
  union { float f; unsigned u; } v; v.f = f;
  unsigned r = v.u + 0x7fffu + ((v.u >> 16) & 1u);
  return (unsigned short)(r >> 16);
}
__device__ __forceinline__ float bf2f(unsigned short h) {
  union { unsigned u; float f; } v; v.u = ((unsigned)h) << 16; return v.f;
}
// pack two f32 -> (bf16(a) low | bf16(b) high), RNE, order guaranteed
__device__ __forceinline__ unsigned pk2(float a, float b) {
  union { float f; unsigned u; } x, y; x.f = a; y.f = b;
  unsigned ra = x.u + 0x7fffu + ((x.u >> 16) & 1u);
  unsigned rb = y.u + 0x7fffu + ((y.u >> 16) & 1u);
  return (ra >> 16) | (rb & 0xffff0000u);
}
__device__ __forceinline__ void gload16(const void* g, void* l) {
  __builtin_amdgcn_global_load_lds(
      (const __attribute__((address_space(1))) void*)g,
      (__attribute__((address_space(3))) void*)l, 16, 0, 0);
}
__device__ __forceinline__ float fexp2(float x) {
#if __has_builtin(__builtin_amdgcn_exp2f)
  return __builtin_amdgcn_exp2f(x);
#else
  return exp2f(x);
#endif
}

// ---------- weights f32 -> bf16 ----------
__global__ __launch_bounds__(256) void wconv_kernel(
    const float* __restrict__ w0, const float* __restrict__ w1,
    const float* __restrict__ w2, const float* __restrict__ w3,
    unsigned short* __restrict__ o0, unsigned short* __restrict__ o1,
    unsigned short* __restrict__ o2, unsigned short* __restrict__ o3) {
  int z = blockIdx.y;
  const float* s = z == 0 ? w0 : z == 1 ? w1 : z == 2 ? w2 : w3;
  unsigned short* d = z == 0 ? o0 : z == 1 ? o1 : z == 2 ? o2 : o3;
  int t = blockIdx.x * 256 + threadIdx.x;
  const f32x4* sp = (const f32x4*)(s + (size_t)t * 8);
  f32x4 a = sp[0], b = sp[1];
  u16x8 r;
  r[0] = f2bf(a[0]); r[1] = f2bf(a[1]); r[2] = f2bf(a[2]); r[3] = f2bf(a[3]);
  r[4] = f2bf(b[0]); r[5] = f2bf(b[1]); r[6] = f2bf(b[2]); r[7] = f2bf(b[3]);
  *(u16x8*)(d + (size_t)t * 8) = r;
}

// ---------- fused transpose + q/k/v projection GEMMs ----------
// A read DIRECTLY from (b, ch, hw) f32 layout; transpose at fragment assembly.
// A staged f32 [32 ch][128 tok] per k-step with tok-chunk XOR swizzle (key = (ch>>3)&3).
// z=0: q; z=1: k (PRE-SCALED by log2e/8); z=2: v (channel-major (b, n, hw))
__global__ __launch_bounds__(256, 3) void gemm_qkv(
    const float* __restrict__ X0, const float* __restrict__ X1,
    const float* __restrict__ X2,
    const unsigned short* __restrict__ B0, const unsigned short* __restrict__ B1,
    const unsigned short* __restrict__ B2,
    unsigned short* __restrict__ O0, unsigned short* __restrict__ O1,
    unsigned short* __restrict__ O2) {
  __shared__ float aTf[2][4096];           // 32 KB: [32 ch][128 tok] x2
  __shared__ unsigned short bT[2][4096];   // 16 KB: [128 n][32 ch] x2
  int z = blockIdx.y;
  const float* X = z == 0 ? X0 : z == 1 ? X1 : X2;
  const unsigned short* BT = z == 0 ? B0 : z == 1 ? B1 : B2;
  // XCD-grouped bm: A-panels L2-resident per XCD across the 4 bn blocks
  int j = blockIdx.x;
  int bm = (j & 7) * 8 + (j >> 5);
  int bn = (j >> 3) & 3;
  int tid = threadIdx.x, lane = tid & 63, w = tid >> 6;
  int wr = w >> 1, wc = w & 1, l15 = lane & 15, lhi = lane >> 4;
  const int m0 = bm * 128, n0 = bn * 128;
  const int b512 = (m0 >> 10) * 512;   // batch * 512 channel rows
  const int hw0 = m0 & 1023;           // hw offset of this token tile

  // A staging: 1024 units (16B = 4 f32 = 4 tok of one ch); unit u:
  // ch = u>>5, phys_chunk = u&31, logical_chunk = phys ^ ((ch>>3)&3)
  const float* asf[4];
  int adoff[4];
#pragma unroll
  for (int i = 0; i < 4; ++i) {
    int u = i * 256 + tid;
    int ch = u >> 5, pc = u & 31;
    int lc = pc ^ ((ch >> 3) & 3);
    asf[i] = X + (size_t)(b512 + ch) * 1024 + hw0 + lc * 4;
    adoff[i] = u * 4;
  }
  // B staging: 512 units, row u>>2, chunk (u&3)^(row&3) (round-7-verified)
  int u0 = tid, u1 = 256 + tid;
  int br0 = u0 >> 2, bc0 = (u0 & 3) ^ (br0 & 3);
  int br1 = u1 >> 2, bc1 = (u1 & 3) ^ (br1 & 3);
  const unsigned short* bsrc0 = BT + (size_t)(n0 + br0) * 512 + bc0 * 8;
  const unsigned short* bsrc1 = BT + (size_t)(n0 + br1) * 512 + bc1 * 8;

#define QSTAGE(bufi, it)                                            \
  do {                                                              \
    gload16(asf[0] + (it) * 32768, &aTf[bufi][adoff[0]]);           \
    gload16(asf[1] + (it) * 32768, &aTf[bufi][adoff[1]]);           \
    gload16(asf[2] + (it) * 32768, &aTf[bufi][adoff[2]]);           \
    gload16(asf[3] + (it) * 32768, &aTf[bufi][adoff[3]]);           \
    gload16(bsrc0 + (it) * 32, &bT[bufi][u0 * 8]);                  \
    gload16(bsrc1 + (it) * 32, &bT[bufi][u1 * 8]);                  \
  } while (0)

  // A fragment f32 offsets (loop-invariant): lane reads 8 ch (stride 128 f32)
  // at swizzled token index; conflict-free by construction.
  int aoffA[4];
#pragma unroll
  for (int mi = 0; mi < 4; ++mi) {
    int tok = wr * 64 + mi * 16 + l15;
    int atok = ((((tok >> 2) ^ lhi) << 2) | (tok & 3));
    aoffA[mi] = lhi * 1024 + atok;
  }
  // B fragment offsets
  int boff[4];
#pragma unroll
  for (int i = 0; i < 4; ++i) {
    int brow = wc * 64 + i * 16 + l15;
    boff[i] = brow * 32 + ((lhi ^ (brow & 3)) * 8);
  }

  f32x4 acc[4][4] = {};

#define QTILE(BUF, IT)                                                        \
  do {                                                                       \
    if ((IT) + 1 < 16) QSTAGE((BUF) ^ 1, (IT) + 1);                           \
    bf16x8 af[4], bfr[4];                                                    \
    _Pragma("unroll") for (int mi = 0; mi < 4; ++mi) {                        \
      union { unsigned u[4]; bf16x8 v; } ap;                                  \
      float a0 = aTf[BUF][aoffA[mi] + 0 * 128];                               \
      float a1 = aTf[BUF][aoffA[mi] + 1 * 128];                               \
      float a2 = aTf[BUF][aoffA[mi] + 2 * 128];                               \
      float a3 = aTf[BUF][aoffA[mi] + 3 * 128];                               \
      float a4 = aTf[BUF][aoffA[mi] + 4 * 128];                               \
      float a5 = aTf[BUF][aoffA[mi] + 5 * 128];                               \
      float a6 = aTf[BUF][aoffA[mi] + 6 * 128];                               \
      float a7 = aTf[BUF][aoffA[mi] + 7 * 128];                               \
      ap.u[0] = pk2(a0, a1); ap.u[1] = pk2(a2, a3);                           \
      ap.u[2] = pk2(a4, a5); ap.u[3] = pk2(a6, a7);                           \
      af[mi] = ap.v;                                                          \
    }                                                                         \
    _Pragma("unroll") for (int ni = 0; ni < 4; ++ni)                          \
        bfr[ni] = *(const bf16x8*)&bT[BUF][boff[ni]];                         \
    __builtin_amdgcn_s_setprio(1);                                           \
    _Pragma("unroll") for (int mi = 0; mi < 4; ++mi)                          \
        _Pragma("unroll") for (int ni = 0; ni < 4; ++ni)                      \
            acc[mi][ni] = MFMA16(af[mi], bfr[ni], acc[mi][ni]);               \
    __builtin_amdgcn_s_setprio(0);                                           \
    __syncthreads();                                                         \
  } while (0)

  QSTAGE(0, 0);
  __syncthreads();
  for (int it2 = 0; it2 < 16; it2 += 2) {
    QTILE(0, it2);
    QTILE(1, it2 + 1);
  }
#undef QTILE
#undef QSTAGE

  float sc = (z == 1) ? (0.125f * 1.44269504f) : 1.0f;
#pragma unroll
  for (int mi = 0; mi < 4; ++mi) {
#pragma unroll
    for (int ni = 0; ni < 4; ++ni) {
      int row = m0 + wr * 64 + mi * 16 + lhi * 4;
      int col = n0 + wc * 64 + ni * 16 + l15;
      if (z < 2) {
        unsigned short* C = z == 0 ? O0 : O1;
#pragma unroll
        for (int j2 = 0; j2 < 4; ++j2)
          C[(size_t)(row + j2) * 512 + col] = f2bf(acc[mi][ni][j2] * sc);
      } else {
        int bb = row >> 10, hw = row & 1023;
        u16x4 p;
        p[0] = f2bf(acc[mi][ni][0]); p[1] = f2bf(acc[mi][ni][1]);
        p[2] = f2bf(acc[mi][ni][2]); p[3] = f2bf(acc[mi][ni][3]);
        *(u16x4*)&O2[(size_t)bb * 524288 + (size_t)col * 1024 + hw] = p;
      }
    }
  }
}

// ---------- final GEMM: x(8192x512)bf16 @ Wo^T -> f32 (b, c, hw) ----------
__global__ __launch_bounds__(256, 4) void gemm_out(const unsigned short* __restrict__ A,
                                                   const unsigned short* __restrict__ BT,
                                                   float* __restrict__ C) {
  __shared__ unsigned short aT[2][128 * 32];
  __shared__ unsigned short bT[2][64 * 32];
  int j = blockIdx.x;
  int bm = (j & 7) * 8 + (j >> 6);
  int bn = (j >> 3) & 7;
  int tid = threadIdx.x, lane = tid & 63, w = tid >> 6;
  int l15 = lane & 15, lhi = lane >> 4;
  const int m0 = bm * 128, n0 = bn * 64;

  int u0 = tid, u1 = 256 + tid;
  int ar0 = u0 >> 2, ac0 = (u0 & 3) ^ (ar0 & 3);
  int ar1 = u1 >> 2, ac1 = (u1 & 3) ^ (ar1 & 3);
  const unsigned short* asrc0 = A + (size_t)(m0 + ar0) * 512 + ac0 * 8;
  const unsigned short* asrc1 = A + (size_t)(m0 + ar1) * 512 + ac1 * 8;
  const unsigned short* bsrc0 = BT + (size_t)(n0 + ar0) * 512 + ac0 * 8;

#define OSTAGE(bufi, it)                                     \
  do {                                                       \
    gload16(asrc0 + (it) * 32, &aT[bufi][u0 * 8]);           \
    gload16(asrc1 + (it) * 32, &aT[bufi][u1 * 8]);           \
    gload16(bsrc0 + (it) * 32, &bT[bufi][u0 * 8]);           \
  } while (0)

  int aoff[2], boff[4];
#pragma unroll
  for (int i = 0; i < 2; ++i) {
    int arow = w * 32 + i * 16 + l15;
    aoff[i] = arow * 32 + ((lhi ^ (arow & 3)) * 8);
  }
#pragma unroll
  for (int i = 0; i < 4; ++i) {
    int brow = i * 16 + l15;
    boff[i] = brow * 32 + ((lhi ^ (brow & 3)) * 8);
  }

  f32x4 acc[2][4] = {};

#define OTILE(BUF, IT)                                                        \
  do {                                                                       \
    if ((IT) + 1 < 16) OSTAGE((BUF) ^ 1, (IT) + 1);                           \
    bf16x8 af[2], bfr[4];                                                    \
    _Pragma("unroll") for (int mi = 0; mi < 2; ++mi)                          \
        af[mi] = *(const bf16x8*)&aT[BUF][aoff[mi]];                          \
    _Pragma("unroll") for (int ni = 0; ni < 4; ++ni)                          \
        bfr[ni] = *(const bf16x8*)&bT[BUF][boff[ni]];                         \
    __builtin_amdgcn_s_setprio(1);                                           \
    _Pragma("unroll") for (int mi = 0; mi < 2; ++mi)                          \
        _Pragma("unroll") for (int ni = 0; ni < 4; ++ni)                      \
            acc[mi][ni] = MFMA16(af[mi], bfr[ni], acc[mi][ni]);               \
    __builtin_amdgcn_s_setprio(0);                                           \
    __syncthreads();                                                         \
  } while (0)

  OSTAGE(0, 0);
  __syncthreads();
  for (int it2 = 0; it2 < 16; it2 += 2) {
    OTILE(0, it2);
    OTILE(1, it2 + 1);
  }
#undef OTILE
#undef OSTAGE

#pragma unroll
  for (int mi = 0; mi < 2; ++mi) {
#pragma unroll
    for (int ni = 0; ni < 4; ++ni) {
      int row = m0 + w * 32 + mi * 16 + lhi * 4;
      int col = n0 + ni * 16 + l15;
      int bb = row >> 10, hw = row & 1023;
      *(f32x4*)&C[(size_t)bb * 524288 + (size_t)col * 1024 + hw] = acc[mi][ni];
    }
  }
}

// ---------- fused flash attention (fixed-shift softmax, swapped QK^T) ----------
// grid 512: xcd-swizzled (bh, qb); 4 waves, QBLK=128 (32 q/wave: 2 subs), KBLK=64
__global__ __launch_bounds__(256, 2) void attn_kernel(
    const unsigned short* __restrict__ q_tok, const unsigned short* __restrict__ k_tok,
    const unsigned short* __restrict__ v_cm, unsigned short* __restrict__ y_hm) {
  __shared__ unsigned short k_lds[2][64 * 64];
  __shared__ unsigned short v_lds[2][64 * 64];
  __shared__ unsigned short p_lds[4][2][16 * 64];

  int bid = blockIdx.x;
  int slot = bid >> 3;
  int bh = (bid & 7) * 8 + (slot >> 3);
  int qb = slot & 7;
  int h = bh & 7, b = bh >> 3;
  int tid = threadIdx.x;
  int lane = tid & 63, w = tid >> 6;
  int l15 = lane & 15, lhi = lane >> 4;

  const unsigned short* kbase = k_tok + (size_t)b * 524288 + h * 64;
  const unsigned short* vbase = v_cm + (size_t)b * 524288 + (size_t)h * 65536;

  int qglob0 = b * 1024 + qb * 128 + w * 32;
  bf16x8 qf[2][2];
#pragma unroll
  for (int sub = 0; sub < 2; ++sub) {
    const unsigned short* qp =
        q_tok + (size_t)(qglob0 + sub * 16 + l15) * 512 + h * 64 + lhi * 8;
    qf[sub][0] = *(const bf16x8*)qp;
    qf[sub][1] = *(const bf16x8*)(qp + 32);
  }

  bf16x8 ones;
#pragma unroll
  for (int i = 0; i < 8; ++i) ones[i] = (__bf16)1.0f;

  int u0 = tid, u1 = 256 + tid;
  int r0 = u0 >> 3, c0 = (u0 & 7) ^ (r0 & 7);
  int r1 = u1 >> 3, c1 = (u1 & 7) ^ (r1 & 7);
  const unsigned short* ksrc0 = kbase + (size_t)r0 * 512 + c0 * 8;
  const unsigned short* ksrc1 = kbase + (size_t)r1 * 512 + c1 * 8;
  const unsigned short* vsrc0 = vbase + (size_t)r0 * 1024 + c0 * 8;
  const unsigned short* vsrc1 = vbase + (size_t)r1 * 1024 + c1 * 8;

#define STAGE(bufi, kti)                                                    \
  do {                                                                      \
    gload16(ksrc0 + (size_t)(kti) * 32768, &k_lds[bufi][u0 * 8]);           \
    gload16(ksrc1 + (size_t)(kti) * 32768, &k_lds[bufi][u1 * 8]);           \
    gload16(vsrc0 + (kti) * 64, &v_lds[bufi][u0 * 8]);                      \
    gload16(vsrc1 + (kti) * 64, &v_lds[bufi][u1 * 8]);                      \
  } while (0)

  int kvoff[4][2];
#pragma unroll
  for (int nt = 0; nt < 4; ++nt) {
    int brow = nt * 16 + l15, sw = brow & 7;
    kvoff[nt][0] = brow * 64 + ((lhi ^ sw) * 8);
    kvoff[nt][1] = brow * 64 + (((4 + lhi) ^ sw) * 8);
  }

  char* pb = (char*)&p_lds[w][0][0];
  int p2 = (l15 & 7) << 1;
  char* pwr[2][4];
  const char* prd[2][2];
#pragma unroll
  for (int sub = 0; sub < 2; ++sub) {
#pragma unroll
    for (int nt = 0; nt < 4; ++nt)
      pwr[sub][nt] = pb + sub * 2048 + l15 * 128 + ((((nt << 2) | lhi) ^ p2) << 3);
#pragma unroll
    for (int kc = 0; kc < 2; ++kc)
      prd[sub][kc] = pb + sub * 2048 + l15 * 128 + ((((kc << 3) | (lhi << 1)) ^ p2) << 3);
  }

  f32x4 ls[2] = {{0.f, 0.f, 0.f, 0.f}, {0.f, 0.f, 0.f, 0.f}};
  f32x4 o[2][4] = {};

#define TILE(BUF, KT)                                                        \
  do {                                                                       \
    if ((KT) + 1 < 16) STAGE((BUF) ^ 1, (KT) + 1);                           \
    const unsigned short* kl = k_lds[BUF];                                   \
    const unsigned short* vl = v_lds[BUF];                                   \
    f32x4 st[2][4];                                                          \
    __builtin_amdgcn_s_setprio(1);                                           \
    _Pragma("unroll") for (int nt = 0; nt < 4; ++nt) {                       \
      bf16x8 kf0 = *(const bf16x8*)&kl[kvoff[nt][0]];                        \
      bf16x8 kf1 = *(const bf16x8*)&kl[kvoff[nt][1]];                        \
      _Pragma("unroll") for (int sub = 0; sub < 2; ++sub) {                  \
        f32x4 a = {0.f, 0.f, 0.f, 0.f};                                      \
        a = MFMA16(kf0, qf[sub][0], a);                                      \
        a = MFMA16(kf1, qf[sub][1], a);                                      \
        st[sub][nt] = a;                                                     \
      }                                                                      \
    }                                                                        \
    __builtin_amdgcn_s_setprio(0);                                           \
    bf16x8 vf[4][2];                                                         \
    _Pragma("unroll") for (int dt = 0; dt < 4; ++dt) {                       \
      vf[dt][0] = *(const bf16x8*)&vl[kvoff[dt][0]];                         \
      vf[dt][1] = *(const bf16x8*)&vl[kvoff[dt][1]];                         \
    }                                                                        \
    _Pragma("unroll") for (int sub = 0; sub < 2; ++sub) {                    \
      _Pragma("unroll") for (int nt = 0; nt < 4; ++nt) {                     \
        float e0 = fexp2(st[sub][nt][0]);                                    \
        float e1 = fexp2(st[sub][nt][1]);                                    \
        float e2 = fexp2(st[sub][nt][2]);                                    \
        float e3 = fexp2(st[sub][nt][3]);                                    \
        uint2 pk;                                                            \
        pk.x = pk2(e0, e1);                                                  \
        pk.y = pk2(e2, e3);                                                  \
        *(uint2*)pwr[sub][nt] = pk;                                          \
      }                                                                      \
    }                                                                        \
    asm volatile("" ::: "memory");                                          \
    bf16x8 pf[2][2];                                                         \
    _Pragma("unroll") for (int sub = 0; sub < 2; ++sub) {                    \
      pf[sub][0] = *(const bf16x8*)prd[sub][0];                              \
      pf[sub][1] = *(const bf16x8*)prd[sub][1];                              \
    }                                                                        \
    __builtin_amdgcn_s_setprio(1);                                           \
    _Pragma("unroll") for (int dt = 0; dt < 4; ++dt) {                       \
      _Pragma("unroll") for (int sub = 0; sub < 2; ++sub) {                  \
        o[sub][dt] = MFMA16(pf[sub][0], vf[dt][0], o[sub][dt]);              \
        o[sub][dt] = MFMA16(pf[sub][1], vf[dt][1], o[sub][dt]);              \
      }                                                                      \
    }                                                                        \
    _Pragma("unroll") for (int sub = 0; sub < 2; ++sub) {                    \
      ls[sub] = MFMA16(pf[sub][0], ones, ls[sub]);                           \
      ls[sub] = MFMA16(pf[sub][1], ones, ls[sub]);                           \
    }                                                                        \
    __builtin_amdgcn_s_setprio(0);                                           \
    __syncthreads();                                                         \
  } while (0)

  STAGE(0, 0);
  __syncthreads();
  for (int kt2 = 0; kt2 < 16; kt2 += 2) {
    TILE(0, kt2);
    TILE(1, kt2 + 1);
  }
#undef TILE
#undef STAGE

#pragma unroll
  for (int sub = 0; sub < 2; ++sub) {
    float inv[4];
#pragma unroll
    for (int r = 0; r < 4; ++r) inv[r] = 1.0f / ls[sub][r];
#pragma unroll
    for (int dt = 0; dt < 4; ++dt) {
#pragma unroll
      for (int r = 0; r < 4; ++r) {
        int q = qglob0 + sub * 16 + lhi * 4 + r;
        size_t idx = (size_t)q * 512 + h * 64 + dt * 16 + l15;
        float res = bf2f(q_tok[idx]);
        y_hm[idx] = f2bf(o[sub][dt][r] * inv[r] + res);
      }
    }
  }
}

// ---------- LayerNorm -> bf16 (with (c m) un-permute at store) ----------
__global__ __launch_bounds__(256) void ln_kernel(
    const unsigned short* __restrict__ y_hm,
    const float* __restrict__ gamma, const float* __restrict__ beta,
    unsigned short* __restrict__ xln) {
  __shared__ float y_s[512];
  __shared__ float red[8];
  int row = blockIdx.x;
  int t = threadIdx.x;
  float y0 = bf2f(y_hm[(size_t)row * 512 + t]);
  float y1 = bf2f(y_hm[(size_t)row * 512 + 256 + t]);
  y_s[t] = y0;
  y_s[t + 256] = y1;
  float s = y0 + y1, ss = y0 * y0 + y1 * y1;
#pragma unroll
  for (int msk = 1; msk < 64; msk <<= 1) {
    s += __shfl_xor(s, msk);
    ss += __shfl_xor(ss, msk);
  }
  int w = t >> 6, lane = t & 63;
  if (lane == 0) { red[w] = s; red[4 + w] = ss; }
  __syncthreads();
  s = (red[0] + red[1]) + (red[2] + red[3]);
  ss = (red[4] + red[5]) + (red[6] + red[7]);
  float mean = s * (1.0f / 512.0f);
  float var = ss * (1.0f / 512.0f) - mean * mean;
  float rstd = rsqrtf(var + 1e-6f);
  int c0 = t, c1 = t + 256;
  int p0 = ((c0 & 7) << 6) | (c0 >> 3);
  int p1 = ((c1 & 7) << 6) | (c1 >> 3);
  xln[(size_t)row * 512 + c0] = f2bf((y_s[p0] - mean) * rstd * gamma[c0] + beta[c0]);
  xln[(size_t)row * 512 + c1] = f2bf((y_s[p1] - mean) * rstd * gamma[c1] + beta[c1]);
}

extern "C" void kernel_launch(void* const* d_in, const int* in_sizes, int n_in,
                              void* d_out, int out_size, void* d_ws, size_t ws_size,
                              hipStream_t stream) {
  const float* key   = (const float*)d_in[0];
  const float* value = (const float*)d_in[1];
  const float* query = (const float*)d_in[2];
  const float* Wq = (const float*)d_in[3];
  const float* Wk = (const float*)d_in[4];
  const float* Wv = (const float*)d_in[5];
  const float* Wo = (const float*)d_in[6];
  const float* gamma = (const float*)d_in[7];
  const float* beta  = (const float*)d_in[8];

  char* ws = (char*)d_ws;
  unsigned short* Wq_b = (unsigned short*)(ws);
  unsigned short* Wk_b = Wq_b + 262144;
  unsigned short* Wv_b = Wk_b + 262144;
  unsigned short* Wo_b = Wv_b + 262144;
  unsigned short* q_tok = (unsigned short*)(ws + (size_t)(26u) * 1048576);
  unsigned short* k_tok = (unsigned short*)(ws + (size_t)(34u) * 1048576);
  unsigned short* v_cm  = (unsigned short*)(ws + (size_t)(42u) * 1048576);
  unsigned short* xln   = (unsigned short*)(ws + (size_t)(2u) * 1048576);
  unsigned short* y_hm  = (unsigned short*)d_out;  // d_out as scratch

  wconv_kernel<<<dim3(128, 4), 256, 0, stream>>>(Wq, Wk, Wv, Wo, Wq_b, Wk_b, Wv_b, Wo_b);
  gemm_qkv<<<dim3(256, 3), 256, 0, stream>>>(query, key, value, Wq_b, Wk_b, Wv_b,
                                             q_tok, k_tok, v_cm);
  attn_kernel<<<512, 256, 0, stream>>>(q_tok, k_tok, v_cm, y_hm);
  ln_kernel<<<8192, 256, 0, stream>>>(y_hm, gamma, beta, xln);
  gemm_out<<<512, 256, 0, stream>>>(xln, Wo_b, (float*)d_out);
}

// Round 13
// 83.577 us; speedup vs baseline: 1.0428x; 1.0428x over previous
//
#include <hip/hip_runtime.h>
#include <stdint.h>

typedef __bf16 bf16x8 __attribute__((ext_vector_type(8)));
typedef float f32x4 __attribute__((ext_vector_type(4)));
typedef unsigned short u16x4 __attribute__((ext_vector_type(4)));
typedef unsigned short u16x8 __attribute__((ext_vector_type(8)));

#define MFMA16(a, b, c) __builtin_amdgcn_mfma_f32_16x16x32_bf16(a, b, c, 0, 0, 0)

__device__ __forceinline__ unsigned short f2bf(float f) {
  union { float f; unsigned u; } v; v.f = f;
  unsigned r = v.u + 0x7fffu + ((v.u >> 16) & 1u);
  return (unsigned short)(r >> 16);
}
__device__ __forceinline__ float bf2f(unsigned short h) {
  union { unsigned u; float f; } v; v.u = ((unsigned)h) << 16; return v.f;
}
// bit-op RNE pack (a -> low half, b -> high half)
__device__ __forceinline__ unsigned pk2(float a, float b) {
  union { float f; unsigned u; } x, y; x.f = a; y.f = b;
  unsigned ra = x.u + 0x7fffu + ((x.u >> 16) & 1u);
  unsigned rb = y.u + 0x7fffu + ((y.u >> 16) & 1u);
  return (ra >> 16) | (rb & 0xffff0000u);
}
// native-cast RNE pack (round-6-verified; compiler may fuse to v_cvt_pk)
__device__ __forceinline__ unsigned pk2c(float a, float b) {
  union { unsigned u; __bf16 h[2]; } v;
  v.h[0] = (__bf16)a;
  v.h[1] = (__bf16)b;
  return v.u;
}
__device__ __forceinline__ void gload16(const void* g, void* l) {
  __builtin_amdgcn_global_load_lds(
      (const __attribute__((address_space(1))) void*)g,
      (__attribute__((address_space(3))) void*)l, 16, 0, 0);
}
__device__ __forceinline__ float fexp2(float x) {
#if __has_builtin(__builtin_amdgcn_exp2f)
  return __builtin_amdgcn_exp2f(x);
#else
  return exp2f(x);
#endif
}

// ---------- weights f32 -> bf16 ----------
__global__ __launch_bounds__(256) void wconv_kernel(
    const float* __restrict__ w0, const float* __restrict__ w1,
    const float* __restrict__ w2, const float* __restrict__ w3,
    unsigned short* __restrict__ o0, unsigned short* __restrict__ o1,
    unsigned short* __restrict__ o2, unsigned short* __restrict__ o3) {
  int z = blockIdx.y;
  const float* s = z == 0 ? w0 : z == 1 ? w1 : z == 2 ? w2 : w3;
  unsigned short* d = z == 0 ? o0 : z == 1 ? o1 : z == 2 ? o2 : o3;
  int t = blockIdx.x * 256 + threadIdx.x;
  const f32x4* sp = (const f32x4*)(s + (size_t)t * 8);
  f32x4 a = sp[0], b = sp[1];
  u16x8 r;
  r[0] = f2bf(a[0]); r[1] = f2bf(a[1]); r[2] = f2bf(a[2]); r[3] = f2bf(a[3]);
  r[4] = f2bf(b[0]); r[5] = f2bf(b[1]); r[6] = f2bf(b[2]); r[7] = f2bf(b[3]);
  *(u16x8*)(d + (size_t)t * 8) = r;
}

// ---------- fused transpose + q/k/v projection GEMMs ----------
// A read from (b, ch, hw) f32 GLOBAL to REGS (coalesced), packed to bf16 once,
// ds_write_b64 TRANSPOSED into [128 tok][40-pad ch] (bank-floor layout);
// fragments via verified swizzled ds_read_b128. B via gload_lds (unchanged).
// z=0: q; z=1: k (PRE-SCALED by log2e/8); z=2: v (channel-major (b, n, hw))
__global__ __launch_bounds__(256, 3) void gemm_qkv(
    const float* __restrict__ X0, const float* __restrict__ X1,
    const float* __restrict__ X2,
    const unsigned short* __restrict__ B0, const unsigned short* __restrict__ B1,
    const unsigned short* __restrict__ B2,
    unsigned short* __restrict__ O0, unsigned short* __restrict__ O1,
    unsigned short* __restrict__ O2) {
  __shared__ unsigned short aB[2][128 * 40];  // 20 KB: [tok][ch] bf16, row pad 40
  __shared__ unsigned short bT[2][128 * 32];  // 16 KB
  int z = blockIdx.y;
  const float* X = z == 0 ? X0 : z == 1 ? X1 : X2;
  const unsigned short* BT = z == 0 ? B0 : z == 1 ? B1 : B2;
  // XCD-grouped bm (A-panel L2 reuse across the 4 bn blocks)
  int j = blockIdx.x;
  int bm = (j & 7) * 8 + (j >> 5);
  int bn = (j >> 3) & 3;
  int tid = threadIdx.x, lane = tid & 63, w = tid >> 6;
  int wr = w >> 1, wc = w & 1, l15 = lane & 15, lhi = lane >> 4;
  const int m0 = bm * 128, n0 = bn * 128;
  const int b512 = (m0 >> 10) * 512;
  const int hw0 = m0 & 1023;

  // ---- A reg-staging mapping: thread owns 4 ch x 4 tok ----
  int tok0 = (tid & 31) * 4;
  int ch0 = (tid >> 5) * 4;
  const float* xbase = X + (size_t)(b512 + ch0) * 1024 + hw0 + tok0;
  // write: tok = tok0+i at u16 idx tok*40 + phys*4 + (ch&3),
  // phys = (ch0>>2) ^ K, K = (tok>>4)&6 (uniform over the 4 i)
  int Kw = ((tid & 31) >> 2) & 6;
  int aw0 = tok0 * 40 + (((ch0 >> 2) ^ Kw) << 2);

  // ---- B staging (verified): 512 units, row u>>2, chunk (u&3)^(row&3) ----
  int u0 = tid, u1 = 256 + tid;
  int br0 = u0 >> 2, bc0 = (u0 & 3) ^ (br0 & 3);
  int br1 = u1 >> 2, bc1 = (u1 & 3) ^ (br1 & 3);
  const unsigned short* bsrc0 = BT + (size_t)(n0 + br0) * 512 + bc0 * 8;
  const unsigned short* bsrc1 = BT + (size_t)(n0 + br1) * 512 + bc1 * 8;

  // ---- fragment offsets (loop-invariant) ----
  // A: tok = wr*64+mi*16+l15; kappa = (tok>>5)&3 = ((wr*4+mi)>>1)&3
  int aoff[4];
#pragma unroll
  for (int mi = 0; mi < 4; ++mi) {
    int T0 = wr * 64 + mi * 16;
    int kap = ((wr * 4 + mi) >> 1) & 3;
    aoff[mi] = (T0 + l15) * 40 + ((lhi ^ kap) << 3);
  }
  int boff[4];
#pragma unroll
  for (int i = 0; i < 4; ++i) {
    int brow = wc * 64 + i * 16 + l15;
    boff[i] = brow * 32 + ((lhi ^ (brow & 3)) * 8);
  }

  f32x4 xr0, xr1, xr2, xr3;  // staging regs (4 ch rows x 4 tok)

#define ALOAD(it)                                                      \
  do {                                                                 \
    xr0 = *(const f32x4*)(xbase + ((it) * 32 + 0) * 1024);             \
    xr1 = *(const f32x4*)(xbase + ((it) * 32 + 1) * 1024);             \
    xr2 = *(const f32x4*)(xbase + ((it) * 32 + 2) * 1024);             \
    xr3 = *(const f32x4*)(xbase + ((it) * 32 + 3) * 1024);             \
  } while (0)

#define AWRITE(bufi)                                                   \
  do {                                                                 \
    _Pragma("unroll") for (int i = 0; i < 4; ++i) {                    \
      uint2 pv;                                                        \
      pv.x = pk2c(xr0[i], xr1[i]);                                     \
      pv.y = pk2c(xr2[i], xr3[i]);                                     \
      *(uint2*)&aB[bufi][aw0 + i * 40] = pv;                           \
    }                                                                  \
  } while (0)

#define BSTAGE(bufi, it)                                               \
  do {                                                                 \
    gload16(bsrc0 + (it) * 32, &bT[bufi][u0 * 8]);                     \
    gload16(bsrc1 + (it) * 32, &bT[bufi][u1 * 8]);                     \
  } while (0)

  f32x4 acc[4][4] = {};

#define QTILE(BUF, IT)                                                        \
  do {                                                                       \
    if ((IT) + 1 < 16) {                                                     \
      ALOAD((IT) + 1);                                                       \
      BSTAGE((BUF) ^ 1, (IT) + 1);                                           \
    }                                                                        \
    bf16x8 af[4], bfr[4];                                                    \
    _Pragma("unroll") for (int mi = 0; mi < 4; ++mi)                          \
        af[mi] = *(const bf16x8*)&aB[BUF][aoff[mi]];                          \
    _Pragma("unroll") for (int ni = 0; ni < 4; ++ni)                          \
        bfr[ni] = *(const bf16x8*)&bT[BUF][boff[ni]];                         \
    __builtin_amdgcn_s_setprio(1);                                           \
    _Pragma("unroll") for (int mi = 0; mi < 4; ++mi)                          \
        _Pragma("unroll") for (int ni = 0; ni < 4; ++ni)                      \
            acc[mi][ni] = MFMA16(af[mi], bfr[ni], acc[mi][ni]);               \
    __builtin_amdgcn_s_setprio(0);                                           \
    if ((IT) + 1 < 16) AWRITE((BUF) ^ 1); /* pack+write after MFMA (T14) */   \
    __syncthreads();                                                         \
  } while (0)

  // prologue: tile 0
  ALOAD(0);
  BSTAGE(0, 0);
  AWRITE(0);
  __syncthreads();
  for (int it2 = 0; it2 < 16; it2 += 2) {
    QTILE(0, it2);
    QTILE(1, it2 + 1);
  }
#undef QTILE
#undef ALOAD
#undef AWRITE
#undef BSTAGE

  float sc = (z == 1) ? (0.125f * 1.44269504f) : 1.0f;
#pragma unroll
  for (int mi = 0; mi < 4; ++mi) {
#pragma unroll
    for (int ni = 0; ni < 4; ++ni) {
      int row = m0 + wr * 64 + mi * 16 + lhi * 4;
      int col = n0 + wc * 64 + ni * 16 + l15;
      if (z < 2) {
        unsigned short* C = z == 0 ? O0 : O1;
#pragma unroll
        for (int j2 = 0; j2 < 4; ++j2)
          C[(size_t)(row + j2) * 512 + col] = f2bf(acc[mi][ni][j2] * sc);
      } else {
        int bb = row >> 10, hw = row & 1023;
        u16x4 p;
        p[0] = f2bf(acc[mi][ni][0]); p[1] = f2bf(acc[mi][ni][1]);
        p[2] = f2bf(acc[mi][ni][2]); p[3] = f2bf(acc[mi][ni][3]);
        *(u16x4*)&O2[(size_t)bb * 524288 + (size_t)col * 1024 + hw] = p;
      }
    }
  }
}

// ---------- final GEMM: x(8192x512)bf16 @ Wo^T -> f32 (b, c, hw) ----------
__global__ __launch_bounds__(256, 4) void gemm_out(const unsigned short* __restrict__ A,
                                                   const unsigned short* __restrict__ BT,
                                                   float* __restrict__ C) {
  __shared__ unsigned short aT[2][128 * 32];
  __shared__ unsigned short bT[2][64 * 32];
  int j = blockIdx.x;
  int bm = (j & 7) * 8 + (j >> 6);
  int bn = (j >> 3) & 7;
  int tid = threadIdx.x, lane = tid & 63, w = tid >> 6;
  int l15 = lane & 15, lhi = lane >> 4;
  const int m0 = bm * 128, n0 = bn * 64;

  int u0 = tid, u1 = 256 + tid;
  int ar0 = u0 >> 2, ac0 = (u0 & 3) ^ (ar0 & 3);
  int ar1 = u1 >> 2, ac1 = (u1 & 3) ^ (ar1 & 3);
  const unsigned short* asrc0 = A + (size_t)(m0 + ar0) * 512 + ac0 * 8;
  const unsigned short* asrc1 = A + (size_t)(m0 + ar1) * 512 + ac1 * 8;
  const unsigned short* bsrc0 = BT + (size_t)(n0 + ar0) * 512 + ac0 * 8;

#define OSTAGE(bufi, it)                                     \
  do {                                                       \
    gload16(asrc0 + (it) * 32, &aT[bufi][u0 * 8]);           \
    gload16(asrc1 + (it) * 32, &aT[bufi][u1 * 8]);           \
    gload16(bsrc0 + (it) * 32, &bT[bufi][u0 * 8]);           \
  } while (0)

  int aoff[2], boff[4];
#pragma unroll
  for (int i = 0; i < 2; ++i) {
    int arow = w * 32 + i * 16 + l15;
    aoff[i] = arow * 32 + ((lhi ^ (arow & 3)) * 8);
  }
#pragma unroll
  for (int i = 0; i < 4; ++i) {
    int brow = i * 16 + l15;
    boff[i] = brow * 32 + ((lhi ^ (brow & 3)) * 8);
  }

  f32x4 acc[2][4] = {};

#define OTILE(BUF, IT)                                                        \
  do {                                                                       \
    if ((IT) + 1 < 16) OSTAGE((BUF) ^ 1, (IT) + 1);                           \
    bf16x8 af[2], bfr[4];                                                    \
    _Pragma("unroll") for (int mi = 0; mi < 2; ++mi)                          \
        af[mi] = *(const bf16x8*)&aT[BUF][aoff[mi]];                          \
    _Pragma("unroll") for (int ni = 0; ni < 4; ++ni)                          \
        bfr[ni] = *(const bf16x8*)&bT[BUF][boff[ni]];                         \
    __builtin_amdgcn_s_setprio(1);                                           \
    _Pragma("unroll") for (int mi = 0; mi < 2; ++mi)                          \
        _Pragma("unroll") for (int ni = 0; ni < 4; ++ni)                      \
            acc[mi][ni] = MFMA16(af[mi], bfr[ni], acc[mi][ni]);               \
    __builtin_amdgcn_s_setprio(0);                                           \
    __syncthreads();                                                         \
  } while (0)

  OSTAGE(0, 0);
  __syncthreads();
  for (int it2 = 0; it2 < 16; it2 += 2) {
    OTILE(0, it2);
    OTILE(1, it2 + 1);
  }
#undef OTILE
#undef OSTAGE

#pragma unroll
  for (int mi = 0; mi < 2; ++mi) {
#pragma unroll
    for (int ni = 0; ni < 4; ++ni) {
      int row = m0 + w * 32 + mi * 16 + lhi * 4;
      int col = n0 + ni * 16 + l15;
      int bb = row >> 10, hw = row & 1023;
      *(f32x4*)&C[(size_t)bb * 524288 + (size_t)col * 1024 + hw] = acc[mi][ni];
    }
  }
}

// ---------- fused flash attention (fixed-shift softmax, swapped QK^T) ----------
// grid 512: xcd-swizzled (bh, qb); 4 waves, QBLK=128 (32 q/wave: 2 subs), KBLK=64
__global__ __launch_bounds__(256, 2) void attn_kernel(
    const unsigned short* __restrict__ q_tok, const unsigned short* __restrict__ k_tok,
    const unsigned short* __restrict__ v_cm, unsigned short* __restrict__ y_hm) {
  __shared__ unsigned short k_lds[2][64 * 64];
  __shared__ unsigned short v_lds[2][64 * 64];
  __shared__ unsigned short p_lds[4][2][16 * 64];

  int bid = blockIdx.x;
  int slot = bid >> 3;
  int bh = (bid & 7) * 8 + (slot >> 3);
  int qb = slot & 7;
  int h = bh & 7, b = bh >> 3;
  int tid = threadIdx.x;
  int lane = tid & 63, w = tid >> 6;
  int l15 = lane & 15, lhi = lane >> 4;

  const unsigned short* kbase = k_tok + (size_t)b * 524288 + h * 64;
  const unsigned short* vbase = v_cm + (size_t)b * 524288 + (size_t)h * 65536;

  int qglob0 = b * 1024 + qb * 128 + w * 32;
  bf16x8 qf[2][2];
#pragma unroll
  for (int sub = 0; sub < 2; ++sub) {
    const unsigned short* qp =
        q_tok + (size_t)(qglob0 + sub * 16 + l15) * 512 + h * 64 + lhi * 8;
    qf[sub][0] = *(const bf16x8*)qp;
    qf[sub][1] = *(const bf16x8*)(qp + 32);
  }

  bf16x8 ones;
#pragma unroll
  for (int i = 0; i < 8; ++i) ones[i] = (__bf16)1.0f;

  int u0 = tid, u1 = 256 + tid;
  int r0 = u0 >> 3, c0 = (u0 & 7) ^ (r0 & 7);
  int r1 = u1 >> 3, c1 = (u1 & 7) ^ (r1 & 7);
  const unsigned short* ksrc0 = kbase + (size_t)r0 * 512 + c0 * 8;
  const unsigned short* ksrc1 = kbase + (size_t)r1 * 512 + c1 * 8;
  const unsigned short* vsrc0 = vbase + (size_t)r0 * 1024 + c0 * 8;
  const unsigned short* vsrc1 = vbase + (size_t)r1 * 1024 + c1 * 8;

#define STAGE(bufi, kti)                                                    \
  do {                                                                      \
    gload16(ksrc0 + (size_t)(kti) * 32768, &k_lds[bufi][u0 * 8]);           \
    gload16(ksrc1 + (size_t)(kti) * 32768, &k_lds[bufi][u1 * 8]);           \
    gload16(vsrc0 + (kti) * 64, &v_lds[bufi][u0 * 8]);                      \
    gload16(vsrc1 + (kti) * 64, &v_lds[bufi][u1 * 8]);                      \
  } while (0)

  int kvoff[4][2];
#pragma unroll
  for (int nt = 0; nt < 4; ++nt) {
    int brow = nt * 16 + l15, sw = brow & 7;
    kvoff[nt][0] = brow * 64 + ((lhi ^ sw) * 8);
    kvoff[nt][1] = brow * 64 + (((4 + lhi) ^ sw) * 8);
  }

  char* pb = (char*)&p_lds[w][0][0];
  int p2 = (l15 & 7) << 1;
  char* pwr[2][4];
  const char* prd[2][2];
#pragma unroll
  for (int sub = 0; sub < 2; ++sub) {
#pragma unroll
    for (int nt = 0; nt < 4; ++nt)
      pwr[sub][nt] = pb + sub * 2048 + l15 * 128 + ((((nt << 2) | lhi) ^ p2) << 3);
#pragma unroll
    for (int kc = 0; kc < 2; ++kc)
      prd[sub][kc] = pb + sub * 2048 + l15 * 128 + ((((kc << 3) | (lhi << 1)) ^ p2) << 3);
  }

  f32x4 ls[2] = {{0.f, 0.f, 0.f, 0.f}, {0.f, 0.f, 0.f, 0.f}};
  f32x4 o[2][4] = {};

#define TILE(BUF, KT)                                                        \
  do {                                                                       \
    if ((KT) + 1 < 16) STAGE((BUF) ^ 1, (KT) + 1);                           \
    const unsigned short* kl = k_lds[BUF];                                   \
    const unsigned short* vl = v_lds[BUF];                                   \
    f32x4 st[2][4];                                                          \
    __builtin_amdgcn_s_setprio(1);                                           \
    _Pragma("unroll") for (int nt = 0; nt < 4; ++nt) {                       \
      bf16x8 kf0 = *(const bf16x8*)&kl[kvoff[nt][0]];                        \
      bf16x8 kf1 = *(const bf16x8*)&kl[kvoff[nt][1]];                        \
      _Pragma("unroll") for (int sub = 0; sub < 2; ++sub) {                  \
        f32x4 a = {0.f, 0.f, 0.f, 0.f};                                      \
        a = MFMA16(kf0, qf[sub][0], a);                                      \
        a = MFMA16(kf1, qf[sub][1], a);                                      \
        st[sub][nt] = a;                                                     \
      }                                                                      \
    }                                                                        \
    __builtin_amdgcn_s_setprio(0);                                           \
    bf16x8 vf[4][2];                                                         \
    _Pragma("unroll") for (int dt = 0; dt < 4; ++dt) {                       \
      vf[dt][0] = *(const bf16x8*)&vl[kvoff[dt][0]];                         \
      vf[dt][1] = *(const bf16x8*)&vl[kvoff[dt][1]];                         \
    }                                                                        \
    _Pragma("unroll") for (int sub = 0; sub < 2; ++sub) {                    \
      _Pragma("unroll") for (int nt = 0; nt < 4; ++nt) {                     \
        float e0 = fexp2(st[sub][nt][0]);                                    \
        float e1 = fexp2(st[sub][nt][1]);                                    \
        float e2 = fexp2(st[sub][nt][2]);                                    \
        float e3 = fexp2(st[sub][nt][3]);                                    \
        uint2 pk;                                                            \
        pk.x = pk2(e0, e1);                                                  \
        pk.y = pk2(e2, e3);                                                  \
        *(uint2*)pwr[sub][nt] = pk;                                          \
      }                                                                      \
    }                                                                        \
    asm volatile("" ::: "memory");                                          \
    bf16x8 pf[2][2];                                                         \
    _Pragma("unroll") for (int sub = 0; sub < 2; ++sub) {                    \
      pf[sub][0] = *(const bf16x8*)prd[sub][0];                              \
      pf[sub][1] = *(const bf16x8*)prd[sub][1];                              \
    }                                                                        \
    __builtin_amdgcn_s_setprio(1);                                           \
    _Pragma("unroll") for (int dt = 0; dt < 4; ++dt) {                       \
      _Pragma("unroll") for (int sub = 0; sub < 2; ++sub) {                  \
        o[sub][dt] = MFMA16(pf[sub][0], vf[dt][0], o[sub][dt]);              \
        o[sub][dt] = MFMA16(pf[sub][1], vf[dt][1], o[sub][dt]);              \
      }                                                                      \
    }                                                                        \
    _Pragma("unroll") for (int sub = 0; sub < 2; ++sub) {                    \
      ls[sub] = MFMA16(pf[sub][0], ones, ls[sub]);                           \
      ls[sub] = MFMA16(pf[sub][1], ones, ls[sub]);                           \
    }                                                                        \
    __builtin_amdgcn_s_setprio(0);                                           \
    __syncthreads();                                                         \
  } while (0)

  STAGE(0, 0);
  __syncthreads();
  for (int kt2 = 0; kt2 < 16; kt2 += 2) {
    TILE(0, kt2);
    TILE(1, kt2 + 1);
  }
#undef TILE
#undef STAGE

#pragma unroll
  for (int sub = 0; sub < 2; ++sub) {
    float inv[4];
#pragma unroll
    for (int r = 0; r < 4; ++r) inv[r] = 1.0f / ls[sub][r];
#pragma unroll
    for (int dt = 0; dt < 4; ++dt) {
#pragma unroll
      for (int r = 0; r < 4; ++r) {
        int q = qglob0 + sub * 16 + lhi * 4 + r;
        size_t idx = (size_t)q * 512 + h * 64 + dt * 16 + l15;
        float res = bf2f(q_tok[idx]);
        y_hm[idx] = f2bf(o[sub][dt][r] * inv[r] + res);
      }
    }
  }
}

// ---------- LayerNorm -> bf16 (with (c m) un-permute at store) ----------
__global__ __launch_bounds__(256) void ln_kernel(
    const unsigned short* __restrict__ y_hm,
    const float* __restrict__ gamma, const float* __restrict__ beta,
    unsigned short* __restrict__ xln) {
  __shared__ float y_s[512];
  __shared__ float red[8];
  int row = blockIdx.x;
  int t = threadIdx.x;
  float y0 = bf2f(y_hm[(size_t)row * 512 + t]);
  float y1 = bf2f(y_hm[(size_t)row * 512 + 256 + t]);
  y_s[t] = y0;
  y_s[t + 256] = y1;
  float s = y0 + y1, ss = y0 * y0 + y1 * y1;
#pragma unroll
  for (int msk = 1; msk < 64; msk <<= 1) {
    s += __shfl_xor(s, msk);
    ss += __shfl_xor(ss, msk);
  }
  int w = t >> 6, lane = t & 63;
  if (lane == 0) { red[w] = s; red[4 + w] = ss; }
  __syncthreads();
  s = (red[0] + red[1]) + (red[2] + red[3]);
  ss = (red[4] + red[5]) + (red[6] + red[7]);
  float mean = s * (1.0f / 512.0f);
  float var = ss * (1.0f / 512.0f) - mean * mean;
  float rstd = rsqrtf(var + 1e-6f);
  int c0 = t, c1 = t + 256;
  int p0 = ((c0 & 7) << 6) | (c0 >> 3);
  int p1 = ((c1 & 7) << 6) | (c1 >> 3);
  xln[(size_t)row * 512 + c0] = f2bf((y_s[p0] - mean) * rstd * gamma[c0] + beta[c0]);
  xln[(size_t)row * 512 + c1] = f2bf((y_s[p1] - mean) * rstd * gamma[c1] + beta[c1]);
}

extern "C" void kernel_launch(void* const* d_in, const int* in_sizes, int n_in,
                              void* d_out, int out_size, void* d_ws, size_t ws_size,
                              hipStream_t stream) {
  const float* key   = (const float*)d_in[0];
  const float* value = (const float*)d_in[1];
  const float* query = (const float*)d_in[2];
  const float* Wq = (const float*)d_in[3];
  const float* Wk = (const float*)d_in[4];
  const float* Wv = (const float*)d_in[5];
  const float* Wo = (const float*)d_in[6];
  const float* gamma = (const float*)d_in[7];
  const float* beta  = (const float*)d_in[8];

  char* ws = (char*)d_ws;
  unsigned short* Wq_b = (unsigned short*)(ws);
  unsigned short* Wk_b = Wq_b + 262144;
  unsigned short* Wv_b = Wk_b + 262144;
  unsigned short* Wo_b = Wv_b + 262144;
  unsigned short* q_tok = (unsigned short*)(ws + (size_t)(26u) * 1048576);
  unsigned short* k_tok = (unsigned short*)(ws + (size_t)(34u) * 1048576);
  unsigned short* v_cm  = (unsigned short*)(ws + (size_t)(42u) * 1048576);
  unsigned short* xln   = (unsigned short*)(ws + (size_t)(2u) * 1048576);
  unsigned short* y_hm  = (unsigned short*)d_out;  // d_out as scratch

  wconv_kernel<<<dim3(128, 4), 256, 0, stream>>>(Wq, Wk, Wv, Wo, Wq_b, Wk_b, Wv_b, Wo_b);
  gemm_qkv<<<dim3(256, 3), 256, 0, stream>>>(query, key, value, Wq_b, Wk_b, Wv_b,
                                             q_tok, k_tok, v_cm);
  attn_kernel<<<512, 256, 0, stream>>>(q_tok, k_tok, v_cm, y_hm);
  ln_kernel<<<8192, 256, 0, stream>>>(y_hm, gamma, beta, xln);
  gemm_out<<<512, 256, 0, stream>>>(xln, Wo_b, (float*)d_out);
}

// Round 14
// 83.481 us; speedup vs baseline: 1.0440x; 1.0011x over previous
//
#include <hip/hip_runtime.h>
#include <stdint.h>

typedef __bf16 bf16x8 __attribute__((ext_vector_type(8)));
typedef float f32x4 __attribute__((ext_vector_type(4)));
typedef unsigned short u16x4 __attribute__((ext_vector_type(4)));
typedef unsigned short u16x8 __attribute__((ext_vector_type(8)));

#define MFMA16(a, b, c) __builtin_amdgcn_mfma_f32_16x16x32_bf16(a, b, c, 0, 0, 0)

__device__ __forceinline__ unsigned short f2bf(float f) {
  union { float f; unsigned u; } v; v.f = f;
  unsigned r = v.u + 0x7fffu + ((v.u >> 16) & 1u);
  return (unsigned short)(r >> 16);
}
__device__ __forceinline__ float bf2f(unsigned short h) {
  union { unsigned u; float f; } v; v.u = ((unsigned)h) << 16; return v.f;
}
// bit-op RNE pack (a -> low half, b -> high half)
__device__ __forceinline__ unsigned pk2(float a, float b) {
  union { float f; unsigned u; } x, y; x.f = a; y.f = b;
  unsigned ra = x.u + 0x7fffu + ((x.u >> 16) & 1u);
  unsigned rb = y.u + 0x7fffu + ((y.u >> 16) & 1u);
  return (ra >> 16) | (rb & 0xffff0000u);
}
// native-cast RNE pack (round-6-verified; compiler may fuse to v_cvt_pk)
__device__ __forceinline__ unsigned pk2c(float a, float b) {
  union { unsigned u; __bf16 h[2]; } v;
  v.h[0] = (__bf16)a;
  v.h[1] = (__bf16)b;
  return v.u;
}
__device__ __forceinline__ void gload16(const void* g, void* l) {
  __builtin_amdgcn_global_load_lds(
      (const __attribute__((address_space(1))) void*)g,
      (__attribute__((address_space(3))) void*)l, 16, 0, 0);
}
__device__ __forceinline__ float fexp2(float x) {
#if __has_builtin(__builtin_amdgcn_exp2f)
  return __builtin_amdgcn_exp2f(x);
#else
  return exp2f(x);
#endif
}

// ---------- weights f32 -> bf16 ----------
__global__ __launch_bounds__(256) void wconv_kernel(
    const float* __restrict__ w0, const float* __restrict__ w1,
    const float* __restrict__ w2, const float* __restrict__ w3,
    unsigned short* __restrict__ o0, unsigned short* __restrict__ o1,
    unsigned short* __restrict__ o2, unsigned short* __restrict__ o3) {
  int z = blockIdx.y;
  const float* s = z == 0 ? w0 : z == 1 ? w1 : z == 2 ? w2 : w3;
  unsigned short* d = z == 0 ? o0 : z == 1 ? o1 : z == 2 ? o2 : o3;
  int t = blockIdx.x * 256 + threadIdx.x;
  const f32x4* sp = (const f32x4*)(s + (size_t)t * 8);
  f32x4 a = sp[0], b = sp[1];
  u16x8 r;
  r[0] = f2bf(a[0]); r[1] = f2bf(a[1]); r[2] = f2bf(a[2]); r[3] = f2bf(a[3]);
  r[4] = f2bf(b[0]); r[5] = f2bf(b[1]); r[6] = f2bf(b[2]); r[7] = f2bf(b[3]);
  *(u16x8*)(d + (size_t)t * 8) = r;
}

// ---------- fused transpose + q/k/v projection GEMMs ----------
// A read from (b, ch, hw) f32 GLOBAL to REGS (coalesced), packed to bf16 once,
// ds_write_b64 TRANSPOSED into [128 tok][40-pad ch] (bank-floor layout);
// fragments via verified swizzled ds_read_b128. B via gload_lds (unchanged).
// z=0: q; z=1: k (PRE-SCALED by log2e/8); z=2: v (channel-major (b, n, hw))
__global__ __launch_bounds__(256, 3) void gemm_qkv(
    const float* __restrict__ X0, const float* __restrict__ X1,
    const float* __restrict__ X2,
    const unsigned short* __restrict__ B0, const unsigned short* __restrict__ B1,
    const unsigned short* __restrict__ B2,
    unsigned short* __restrict__ O0, unsigned short* __restrict__ O1,
    unsigned short* __restrict__ O2) {
  __shared__ unsigned short aB[2][128 * 40];  // 20 KB: [tok][ch] bf16, row pad 40
  __shared__ unsigned short bT[2][128 * 32];  // 16 KB
  int z = blockIdx.y;
  const float* X = z == 0 ? X0 : z == 1 ? X1 : X2;
  const unsigned short* BT = z == 0 ? B0 : z == 1 ? B1 : B2;
  // XCD-grouped bm (A-panel L2 reuse across the 4 bn blocks)
  int j = blockIdx.x;
  int bm = (j & 7) * 8 + (j >> 5);
  int bn = (j >> 3) & 3;
  int tid = threadIdx.x, lane = tid & 63, w = tid >> 6;
  int wr = w >> 1, wc = w & 1, l15 = lane & 15, lhi = lane >> 4;
  const int m0 = bm * 128, n0 = bn * 128;
  const int b512 = (m0 >> 10) * 512;
  const int hw0 = m0 & 1023;

  // ---- A reg-staging mapping: thread owns 4 ch x 4 tok ----
  int tok0 = (tid & 31) * 4;
  int ch0 = (tid >> 5) * 4;
  const float* xbase = X + (size_t)(b512 + ch0) * 1024 + hw0 + tok0;
  // write: tok = tok0+i at u16 idx tok*40 + phys*4 + (ch&3),
  // phys = (ch0>>2) ^ K, K = (tok>>4)&6 (uniform over the 4 i)
  int Kw = ((tid & 31) >> 2) & 6;
  int aw0 = tok0 * 40 + (((ch0 >> 2) ^ Kw) << 2);

  // ---- B staging (verified): 512 units, row u>>2, chunk (u&3)^(row&3) ----
  int u0 = tid, u1 = 256 + tid;
  int br0 = u0 >> 2, bc0 = (u0 & 3) ^ (br0 & 3);
  int br1 = u1 >> 2, bc1 = (u1 & 3) ^ (br1 & 3);
  const unsigned short* bsrc0 = BT + (size_t)(n0 + br0) * 512 + bc0 * 8;
  const unsigned short* bsrc1 = BT + (size_t)(n0 + br1) * 512 + bc1 * 8;

  // ---- fragment offsets (loop-invariant) ----
  // A: tok = wr*64+mi*16+l15; kappa = (tok>>5)&3 = ((wr*4+mi)>>1)&3
  int aoff[4];
#pragma unroll
  for (int mi = 0; mi < 4; ++mi) {
    int T0 = wr * 64 + mi * 16;
    int kap = ((wr * 4 + mi) >> 1) & 3;
    aoff[mi] = (T0 + l15) * 40 + ((lhi ^ kap) << 3);
  }
  int boff[4];
#pragma unroll
  for (int i = 0; i < 4; ++i) {
    int brow = wc * 64 + i * 16 + l15;
    boff[i] = brow * 32 + ((lhi ^ (brow & 3)) * 8);
  }

  f32x4 xr0, xr1, xr2, xr3;  // staging regs (4 ch rows x 4 tok)

#define ALOAD(it)                                                      \
  do {                                                                 \
    xr0 = *(const f32x4*)(xbase + ((it) * 32 + 0) * 1024);             \
    xr1 = *(const f32x4*)(xbase + ((it) * 32 + 1) * 1024);             \
    xr2 = *(const f32x4*)(xbase + ((it) * 32 + 2) * 1024);             \
    xr3 = *(const f32x4*)(xbase + ((it) * 32 + 3) * 1024);             \
  } while (0)

#define AWRITE(bufi)                                                   \
  do {                                                                 \
    _Pragma("unroll") for (int i = 0; i < 4; ++i) {                    \
      uint2 pv;                                                        \
      pv.x = pk2c(xr0[i], xr1[i]);                                     \
      pv.y = pk2c(xr2[i], xr3[i]);                                     \
      *(uint2*)&aB[bufi][aw0 + i * 40] = pv;                           \
    }                                                                  \
  } while (0)

#define BSTAGE(bufi, it)                                               \
  do {                                                                 \
    gload16(bsrc0 + (it) * 32, &bT[bufi][u0 * 8]);                     \
    gload16(bsrc1 + (it) * 32, &bT[bufi][u1 * 8]);                     \
  } while (0)

  f32x4 acc[4][4] = {};

#define QTILE(BUF, IT)                                                        \
  do {                                                                       \
    if ((IT) + 1 < 16) {                                                     \
      ALOAD((IT) + 1);                                                       \
      BSTAGE((BUF) ^ 1, (IT) + 1);                                           \
    }                                                                        \
    bf16x8 af[4], bfr[4];                                                    \
    _Pragma("unroll") for (int mi = 0; mi < 4; ++mi)                          \
        af[mi] = *(const bf16x8*)&aB[BUF][aoff[mi]];                          \
    _Pragma("unroll") for (int ni = 0; ni < 4; ++ni)                          \
        bfr[ni] = *(const bf16x8*)&bT[BUF][boff[ni]];                         \
    __builtin_amdgcn_s_setprio(1);                                           \
    _Pragma("unroll") for (int mi = 0; mi < 4; ++mi)                          \
        _Pragma("unroll") for (int ni = 0; ni < 4; ++ni)                      \
            acc[mi][ni] = MFMA16(af[mi], bfr[ni], acc[mi][ni]);               \
    __builtin_amdgcn_s_setprio(0);                                           \
    if ((IT) + 1 < 16) AWRITE((BUF) ^ 1); /* pack+write after MFMA (T14) */   \
    __syncthreads();                                                         \
  } while (0)

  // prologue: tile 0
  ALOAD(0);
  BSTAGE(0, 0);
  AWRITE(0);
  __syncthreads();
  for (int it2 = 0; it2 < 16; it2 += 2) {
    QTILE(0, it2);
    QTILE(1, it2 + 1);
  }
#undef QTILE
#undef ALOAD
#undef AWRITE
#undef BSTAGE

  float sc = (z == 1) ? (0.125f * 1.44269504f) : 1.0f;
#pragma unroll
  for (int mi = 0; mi < 4; ++mi) {
#pragma unroll
    for (int ni = 0; ni < 4; ++ni) {
      int row = m0 + wr * 64 + mi * 16 + lhi * 4;
      int col = n0 + wc * 64 + ni * 16 + l15;
      if (z < 2) {
        unsigned short* C = z == 0 ? O0 : O1;
#pragma unroll
        for (int j2 = 0; j2 < 4; ++j2)
          C[(size_t)(row + j2) * 512 + col] = f2bf(acc[mi][ni][j2] * sc);
      } else {
        int bb = row >> 10, hw = row & 1023;
        u16x4 p;
        p[0] = f2bf(acc[mi][ni][0]); p[1] = f2bf(acc[mi][ni][1]);
        p[2] = f2bf(acc[mi][ni][2]); p[3] = f2bf(acc[mi][ni][3]);
        *(u16x4*)&O2[(size_t)bb * 524288 + (size_t)col * 1024 + hw] = p;
      }
    }
  }
}

// ---------- final GEMM: x(8192x512)bf16 @ Wo^T -> f32 (b, c, hw) ----------
__global__ __launch_bounds__(256, 4) void gemm_out(const unsigned short* __restrict__ A,
                                                   const unsigned short* __restrict__ BT,
                                                   float* __restrict__ C) {
  __shared__ unsigned short aT[2][128 * 32];
  __shared__ unsigned short bT[2][64 * 32];
  int j = blockIdx.x;
  int bm = (j & 7) * 8 + (j >> 6);
  int bn = (j >> 3) & 7;
  int tid = threadIdx.x, lane = tid & 63, w = tid >> 6;
  int l15 = lane & 15, lhi = lane >> 4;
  const int m0 = bm * 128, n0 = bn * 64;

  int u0 = tid, u1 = 256 + tid;
  int ar0 = u0 >> 2, ac0 = (u0 & 3) ^ (ar0 & 3);
  int ar1 = u1 >> 2, ac1 = (u1 & 3) ^ (ar1 & 3);
  const unsigned short* asrc0 = A + (size_t)(m0 + ar0) * 512 + ac0 * 8;
  const unsigned short* asrc1 = A + (size_t)(m0 + ar1) * 512 + ac1 * 8;
  const unsigned short* bsrc0 = BT + (size_t)(n0 + ar0) * 512 + ac0 * 8;

#define OSTAGE(bufi, it)                                     \
  do {                                                       \
    gload16(asrc0 + (it) * 32, &aT[bufi][u0 * 8]);           \
    gload16(asrc1 + (it) * 32, &aT[bufi][u1 * 8]);           \
    gload16(bsrc0 + (it) * 32, &bT[bufi][u0 * 8]);           \
  } while (0)

  int aoff[2], boff[4];
#pragma unroll
  for (int i = 0; i < 2; ++i) {
    int arow = w * 32 + i * 16 + l15;
    aoff[i] = arow * 32 + ((lhi ^ (arow & 3)) * 8);
  }
#pragma unroll
  for (int i = 0; i < 4; ++i) {
    int brow = i * 16 + l15;
    boff[i] = brow * 32 + ((lhi ^ (brow & 3)) * 8);
  }

  f32x4 acc[2][4] = {};

#define OTILE(BUF, IT)                                                        \
  do {                                                                       \
    if ((IT) + 1 < 16) OSTAGE((BUF) ^ 1, (IT) + 1);                           \
    bf16x8 af[2], bfr[4];                                                    \
    _Pragma("unroll") for (int mi = 0; mi < 2; ++mi)                          \
        af[mi] = *(const bf16x8*)&aT[BUF][aoff[mi]];                          \
    _Pragma("unroll") for (int ni = 0; ni < 4; ++ni)                          \
        bfr[ni] = *(const bf16x8*)&bT[BUF][boff[ni]];                         \
    __builtin_amdgcn_s_setprio(1);                                           \
    _Pragma("unroll") for (int mi = 0; mi < 2; ++mi)                          \
        _Pragma("unroll") for (int ni = 0; ni < 4; ++ni)                      \
            acc[mi][ni] = MFMA16(af[mi], bfr[ni], acc[mi][ni]);               \
    __builtin_amdgcn_s_setprio(0);                                           \
    __syncthreads();                                                         \
  } while (0)

  OSTAGE(0, 0);
  __syncthreads();
  for (int it2 = 0; it2 < 16; it2 += 2) {
    OTILE(0, it2);
    OTILE(1, it2 + 1);
  }
#undef OTILE
#undef OSTAGE

#pragma unroll
  for (int mi = 0; mi < 2; ++mi) {
#pragma unroll
    for (int ni = 0; ni < 4; ++ni) {
      int row = m0 + w * 32 + mi * 16 + lhi * 4;
      int col = n0 + ni * 16 + l15;
      int bb = row >> 10, hw = row & 1023;
      *(f32x4*)&C[(size_t)bb * 524288 + (size_t)col * 1024 + hw] = acc[mi][ni];
    }
  }
}

// ---------- fused flash attention (fixed-shift softmax, swapped QK^T) ----------
// grid 512: xcd-swizzled (bh, qb); 4 waves, QBLK=128 (32 q/wave: 2 subs), KBLK=64
__global__ __launch_bounds__(256, 2) void attn_kernel(
    const unsigned short* __restrict__ q_tok, const unsigned short* __restrict__ k_tok,
    const unsigned short* __restrict__ v_cm, unsigned short* __restrict__ y_hm) {
  __shared__ unsigned short k_lds[2][64 * 64];
  __shared__ unsigned short v_lds[2][64 * 64];
  __shared__ unsigned short p_lds[4][2][16 * 64];

  int bid = blockIdx.x;
  int slot = bid >> 3;
  int bh = (bid & 7) * 8 + (slot >> 3);
  int qb = slot & 7;
  int h = bh & 7, b = bh >> 3;
  int tid = threadIdx.x;
  int lane = tid & 63, w = tid >> 6;
  int l15 = lane & 15, lhi = lane >> 4;

  const unsigned short* kbase = k_tok + (size_t)b * 524288 + h * 64;
  const unsigned short* vbase = v_cm + (size_t)b * 524288 + (size_t)h * 65536;

  int qglob0 = b * 1024 + qb * 128 + w * 32;
  bf16x8 qf[2][2];
#pragma unroll
  for (int sub = 0; sub < 2; ++sub) {
    const unsigned short* qp =
        q_tok + (size_t)(qglob0 + sub * 16 + l15) * 512 + h * 64 + lhi * 8;
    qf[sub][0] = *(const bf16x8*)qp;
    qf[sub][1] = *(const bf16x8*)(qp + 32);
  }

  bf16x8 ones;
#pragma unroll
  for (int i = 0; i < 8; ++i) ones[i] = (__bf16)1.0f;

  int u0 = tid, u1 = 256 + tid;
  int r0 = u0 >> 3, c0 = (u0 & 7) ^ (r0 & 7);
  int r1 = u1 >> 3, c1 = (u1 & 7) ^ (r1 & 7);
  const unsigned short* ksrc0 = kbase + (size_t)r0 * 512 + c0 * 8;
  const unsigned short* ksrc1 = kbase + (size_t)r1 * 512 + c1 * 8;
  const unsigned short* vsrc0 = vbase + (size_t)r0 * 1024 + c0 * 8;
  const unsigned short* vsrc1 = vbase + (size_t)r1 * 1024 + c1 * 8;

#define STAGE(bufi, kti)                                                    \
  do {                                                                      \
    gload16(ksrc0 + (size_t)(kti) * 32768, &k_lds[bufi][u0 * 8]);           \
    gload16(ksrc1 + (size_t)(kti) * 32768, &k_lds[bufi][u1 * 8]);           \
    gload16(vsrc0 + (kti) * 64, &v_lds[bufi][u0 * 8]);                      \
    gload16(vsrc1 + (kti) * 64, &v_lds[bufi][u1 * 8]);                      \
  } while (0)

  int kvoff[4][2];
#pragma unroll
  for (int nt = 0; nt < 4; ++nt) {
    int brow = nt * 16 + l15, sw = brow & 7;
    kvoff[nt][0] = brow * 64 + ((lhi ^ sw) * 8);
    kvoff[nt][1] = brow * 64 + (((4 + lhi) ^ sw) * 8);
  }

  char* pb = (char*)&p_lds[w][0][0];
  int p2 = (l15 & 7) << 1;
  char* pwr[2][4];
  const char* prd[2][2];
#pragma unroll
  for (int sub = 0; sub < 2; ++sub) {
#pragma unroll
    for (int nt = 0; nt < 4; ++nt)
      pwr[sub][nt] = pb + sub * 2048 + l15 * 128 + ((((nt << 2) | lhi) ^ p2) << 3);
#pragma unroll
    for (int kc = 0; kc < 2; ++kc)
      prd[sub][kc] = pb + sub * 2048 + l15 * 128 + ((((kc << 3) | (lhi << 1)) ^ p2) << 3);
  }

  f32x4 ls[2] = {{0.f, 0.f, 0.f, 0.f}, {0.f, 0.f, 0.f, 0.f}};
  f32x4 o[2][4] = {};

#define TILE(BUF, KT)                                                        \
  do {                                                                       \
    if ((KT) + 1 < 16) STAGE((BUF) ^ 1, (KT) + 1);                           \
    const unsigned short* kl = k_lds[BUF];                                   \
    const unsigned short* vl = v_lds[BUF];                                   \
    f32x4 st[2][4];                                                          \
    __builtin_amdgcn_s_setprio(1);                                           \
    _Pragma("unroll") for (int nt = 0; nt < 4; ++nt) {                       \
      bf16x8 kf0 = *(const bf16x8*)&kl[kvoff[nt][0]];                        \
      bf16x8 kf1 = *(const bf16x8*)&kl[kvoff[nt][1]];                        \
      _Pragma("unroll") for (int sub = 0; sub < 2; ++sub) {                  \
        f32x4 a = {0.f, 0.f, 0.f, 0.f};                                      \
        a = MFMA16(kf0, qf[sub][0], a);                                      \
        a = MFMA16(kf1, qf[sub][1], a);                                      \
        st[sub][nt] = a;                                                     \
      }                                                                      \
    }                                                                        \
    __builtin_amdgcn_s_setprio(0);                                           \
    bf16x8 vf[4][2];                                                         \
    _Pragma("unroll") for (int dt = 0; dt < 4; ++dt) {                       \
      vf[dt][0] = *(const bf16x8*)&vl[kvoff[dt][0]];                         \
      vf[dt][1] = *(const bf16x8*)&vl[kvoff[dt][1]];                         \
    }                                                                        \
    _Pragma("unroll") for (int sub = 0; sub < 2; ++sub) {                    \
      _Pragma("unroll") for (int nt = 0; nt < 4; ++nt) {                     \
        float e0 = fexp2(st[sub][nt][0]);                                    \
        float e1 = fexp2(st[sub][nt][1]);                                    \
        float e2 = fexp2(st[sub][nt][2]);                                    \
        float e3 = fexp2(st[sub][nt][3]);                                    \
        uint2 pk;                                                            \
        pk.x = pk2(e0, e1);                                                  \
        pk.y = pk2(e2, e3);                                                  \
        *(uint2*)pwr[sub][nt] = pk;                                          \
      }                                                                      \
    }                                                                        \
    asm volatile("" ::: "memory");                                          \
    bf16x8 pf[2][2];                                                         \
    _Pragma("unroll") for (int sub = 0; sub < 2; ++sub) {                    \
      pf[sub][0] = *(const bf16x8*)prd[sub][0];                              \
      pf[sub][1] = *(const bf16x8*)prd[sub][1];                              \
    }                                                                        \
    __builtin_amdgcn_s_setprio(1);                                           \
    _Pragma("unroll") for (int dt = 0; dt < 4; ++dt) {                       \
      _Pragma("unroll") for (int sub = 0; sub < 2; ++sub) {                  \
        o[sub][dt] = MFMA16(pf[sub][0], vf[dt][0], o[sub][dt]);              \
        o[sub][dt] = MFMA16(pf[sub][1], vf[dt][1], o[sub][dt]);              \
      }                                                                      \
    }                                                                        \
    _Pragma("unroll") for (int sub = 0; sub < 2; ++sub) {                    \
      ls[sub] = MFMA16(pf[sub][0], ones, ls[sub]);                           \
      ls[sub] = MFMA16(pf[sub][1], ones, ls[sub]);                           \
    }                                                                        \
    __builtin_amdgcn_s_setprio(0);                                           \
    __syncthreads();                                                         \
  } while (0)

  STAGE(0, 0);
  __syncthreads();
  for (int kt2 = 0; kt2 < 16; kt2 += 2) {
    TILE(0, kt2);
    TILE(1, kt2 + 1);
  }
#undef TILE
#undef STAGE

#pragma unroll
  for (int sub = 0; sub < 2; ++sub) {
    float inv[4];
#pragma unroll
    for (int r = 0; r < 4; ++r) inv[r] = 1.0f / ls[sub][r];
#pragma unroll
    for (int dt = 0; dt < 4; ++dt) {
#pragma unroll
      for (int r = 0; r < 4; ++r) {
        int q = qglob0 + sub * 16 + lhi * 4 + r;
        size_t idx = (size_t)q * 512 + h * 64 + dt * 16 + l15;
        float res = bf2f(q_tok[idx]);
        y_hm[idx] = f2bf(o[sub][dt][r] * inv[r] + res);
      }
    }
  }
}

// ---------- LayerNorm -> bf16 (with (c m) un-permute at store) ----------
__global__ __launch_bounds__(256) void ln_kernel(
    const unsigned short* __restrict__ y_hm,
    const float* __restrict__ gamma, const float* __restrict__ beta,
    unsigned short* __restrict__ xln) {
  __shared__ float y_s[512];
  __shared__ float red[8];
  int row = blockIdx.x;
  int t = threadIdx.x;
  float y0 = bf2f(y_hm[(size_t)row * 512 + t]);
  float y1 = bf2f(y_hm[(size_t)row * 512 + 256 + t]);
  y_s[t] = y0;
  y_s[t + 256] = y1;
  float s = y0 + y1, ss = y0 * y0 + y1 * y1;
#pragma unroll
  for (int msk = 1; msk < 64; msk <<= 1) {
    s += __shfl_xor(s, msk);
    ss += __shfl_xor(ss, msk);
  }
  int w = t >> 6, lane = t & 63;
  if (lane == 0) { red[w] = s; red[4 + w] = ss; }
  __syncthreads();
  s = (red[0] + red[1]) + (red[2] + red[3]);
  ss = (red[4] + red[5]) + (red[6] + red[7]);
  float mean = s * (1.0f / 512.0f);
  float var = ss * (1.0f / 512.0f) - mean * mean;
  float rstd = rsqrtf(var + 1e-6f);
  int c0 = t, c1 = t + 256;
  int p0 = ((c0 & 7) << 6) | (c0 >> 3);
  int p1 = ((c1 & 7) << 6) | (c1 >> 3);
  xln[(size_t)row * 512 + c0] = f2bf((y_s[p0] - mean) * rstd * gamma[c0] + beta[c0]);
  xln[(size_t)row * 512 + c1] = f2bf((y_s[p1] - mean) * rstd * gamma[c1] + beta[c1]);
}

extern "C" void kernel_launch(void* const* d_in, const int* in_sizes, int n_in,
                              void* d_out, int out_size, void* d_ws, size_t ws_size,
                              hipStream_t stream) {
  const float* key   = (const float*)d_in[0];
  const float* value = (const float*)d_in[1];
  const float* query = (const float*)d_in[2];
  const float* Wq = (const float*)d_in[3];
  const float* Wk = (const float*)d_in[4];
  const float* Wv = (const float*)d_in[5];
  const float* Wo = (const float*)d_in[6];
  const float* gamma = (const float*)d_in[7];
  const float* beta  = (const float*)d_in[8];

  char* ws = (char*)d_ws;
  unsigned short* Wq_b = (unsigned short*)(ws);
  unsigned short* Wk_b = Wq_b + 262144;
  unsigned short* Wv_b = Wk_b + 262144;
  unsigned short* Wo_b = Wv_b + 262144;
  unsigned short* q_tok = (unsigned short*)(ws + (size_t)(26u) * 1048576);
  unsigned short* k_tok = (unsigned short*)(ws + (size_t)(34u) * 1048576);
  unsigned short* v_cm  = (unsigned short*)(ws + (size_t)(42u) * 1048576);
  unsigned short* xln   = (unsigned short*)(ws + (size_t)(2u) * 1048576);
  unsigned short* y_hm  = (unsigned short*)d_out;  // d_out as scratch

  wconv_kernel<<<dim3(128, 4), 256, 0, stream>>>(Wq, Wk, Wv, Wo, Wq_b, Wk_b, Wv_b, Wo_b);
  gemm_qkv<<<dim3(256, 3), 256, 0, stream>>>(query, key, value, Wq_b, Wk_b, Wv_b,
                                             q_tok, k_tok, v_cm);
  attn_kernel<<<512, 256, 0, stream>>>(q_tok, k_tok, v_cm, y_hm);
  ln_kernel<<<8192, 256, 0, stream>>>(y_hm, gamma, beta, xln);
  gemm_out<<<512, 256, 0, stream>>>(xln, Wo_b, (float*)d_out);
}

// Round 15
// 83.329 us; speedup vs baseline: 1.0459x; 1.0018x over previous
//
#include <hip/hip_runtime.h>
#include <stdint.h>

typedef __bf16 bf16x8 __attribute__((ext_vector_type(8)));
typedef float f32x4 __attribute__((ext_vector_type(4)));
typedef unsigned short u16x4 __attribute__((ext_vector_type(4)));
typedef unsigned short u16x8 __attribute__((ext_vector_type(8)));

#define MFMA16(a, b, c) __builtin_amdgcn_mfma_f32_16x16x32_bf16(a, b, c, 0, 0, 0)

__device__ __forceinline__ unsigned short f2bf(float f) {
  union { float f; unsigned u; } v; v.f = f;
  unsigned r = v.u + 0x7fffu + ((v.u >> 16) & 1u);
  return (unsigned short)(r >> 16);
}
__device__ __forceinline__ float bf2f(unsigned short h) {
  union { unsigned u; float f; } v; v.u = ((unsigned)h) << 16; return v.f;
}
// bit-op RNE pack (a -> low half, b -> high half)
__device__ __forceinline__ unsigned pk2(float a, float b) {
  union { float f; unsigned u; } x, y; x.f = a; y.f = b;
  unsigned ra = x.u + 0x7fffu + ((x.u >> 16) & 1u);
  unsigned rb = y.u + 0x7fffu + ((y.u >> 16) & 1u);
  return (ra >> 16) | (rb & 0xffff0000u);
}
// native-cast RNE pack (round-6-verified; compiler may fuse to v_cvt_pk)
__device__ __forceinline__ unsigned pk2c(float a, float b) {
  union { unsigned u; __bf16 h[2]; } v;
  v.h[0] = (__bf16)a;
  v.h[1] = (__bf16)b;
  return v.u;
}
__device__ __forceinline__ void gload16(const void* g, void* l) {
  __builtin_amdgcn_global_load_lds(
      (const __attribute__((address_space(1))) void*)g,
      (__attribute__((address_space(3))) void*)l, 16, 0, 0);
}
__device__ __forceinline__ float fexp2(float x) {
#if __has_builtin(__builtin_amdgcn_exp2f)
  return __builtin_amdgcn_exp2f(x);
#else
  return exp2f(x);
#endif
}

// ---------- weights f32 -> bf16 ----------
__global__ __launch_bounds__(256) void wconv_kernel(
    const float* __restrict__ w0, const float* __restrict__ w1,
    const float* __restrict__ w2, const float* __restrict__ w3,
    unsigned short* __restrict__ o0, unsigned short* __restrict__ o1,
    unsigned short* __restrict__ o2, unsigned short* __restrict__ o3) {
  int z = blockIdx.y;
  const float* s = z == 0 ? w0 : z == 1 ? w1 : z == 2 ? w2 : w3;
  unsigned short* d = z == 0 ? o0 : z == 1 ? o1 : z == 2 ? o2 : o3;
  int t = blockIdx.x * 256 + threadIdx.x;
  const f32x4* sp = (const f32x4*)(s + (size_t)t * 8);
  f32x4 a = sp[0], b = sp[1];
  u16x8 r;
  r[0] = f2bf(a[0]); r[1] = f2bf(a[1]); r[2] = f2bf(a[2]); r[3] = f2bf(a[3]);
  r[4] = f2bf(b[0]); r[5] = f2bf(b[1]); r[6] = f2bf(b[2]); r[7] = f2bf(b[3]);
  *(u16x8*)(d + (size_t)t * 8) = r;
}

// ---------- fused transpose + q/k/v projection GEMMs ----------
// A read from (b, ch, hw) f32 GLOBAL to REGS (coalesced), packed to bf16 once,
// ds_write_b64 TRANSPOSED into [128 tok][40-pad ch] (bank-floor layout);
// fragments via verified swizzled ds_read_b128. B via gload_lds (unchanged).
// z=0: q; z=1: k (PRE-SCALED by log2e/8); z=2: v (channel-major (b, n, hw))
__global__ __launch_bounds__(256, 3) void gemm_qkv(
    const float* __restrict__ X0, const float* __restrict__ X1,
    const float* __restrict__ X2,
    const unsigned short* __restrict__ B0, const unsigned short* __restrict__ B1,
    const unsigned short* __restrict__ B2,
    unsigned short* __restrict__ O0, unsigned short* __restrict__ O1,
    unsigned short* __restrict__ O2) {
  __shared__ unsigned short aB[2][128 * 40];  // 20 KB: [tok][ch] bf16, row pad 40
  __shared__ unsigned short bT[2][128 * 32];  // 16 KB
  int z = blockIdx.y;
  const float* X = z == 0 ? X0 : z == 1 ? X1 : X2;
  const unsigned short* BT = z == 0 ? B0 : z == 1 ? B1 : B2;
  // XCD-grouped bm (A-panel L2 reuse across the 4 bn blocks)
  int j = blockIdx.x;
  int bm = (j & 7) * 8 + (j >> 5);
  int bn = (j >> 3) & 3;
  int tid = threadIdx.x, lane = tid & 63, w = tid >> 6;
  int wr = w >> 1, wc = w & 1, l15 = lane & 15, lhi = lane >> 4;
  const int m0 = bm * 128, n0 = bn * 128;
  const int b512 = (m0 >> 10) * 512;
  const int hw0 = m0 & 1023;

  // ---- A reg-staging mapping: thread owns 4 ch x 4 tok ----
  int tok0 = (tid & 31) * 4;
  int ch0 = (tid >> 5) * 4;
  const float* xbase = X + (size_t)(b512 + ch0) * 1024 + hw0 + tok0;
  // write: tok = tok0+i at u16 idx tok*40 + phys*4 + (ch&3),
  // phys = (ch0>>2) ^ K, K = (tok>>4)&6 (uniform over the 4 i)
  int Kw = ((tid & 31) >> 2) & 6;
  int aw0 = tok0 * 40 + (((ch0 >> 2) ^ Kw) << 2);

  // ---- B staging (verified): 512 units, row u>>2, chunk (u&3)^(row&3) ----
  int u0 = tid, u1 = 256 + tid;
  int br0 = u0 >> 2, bc0 = (u0 & 3) ^ (br0 & 3);
  int br1 = u1 >> 2, bc1 = (u1 & 3) ^ (br1 & 3);
  const unsigned short* bsrc0 = BT + (size_t)(n0 + br0) * 512 + bc0 * 8;
  const unsigned short* bsrc1 = BT + (size_t)(n0 + br1) * 512 + bc1 * 8;

  // ---- fragment offsets (loop-invariant) ----
  // A: tok = wr*64+mi*16+l15; kappa = (tok>>5)&3 = ((wr*4+mi)>>1)&3
  int aoff[4];
#pragma unroll
  for (int mi = 0; mi < 4; ++mi) {
    int T0 = wr * 64 + mi * 16;
    int kap = ((wr * 4 + mi) >> 1) & 3;
    aoff[mi] = (T0 + l15) * 40 + ((lhi ^ kap) << 3);
  }
  int boff[4];
#pragma unroll
  for (int i = 0; i < 4; ++i) {
    int brow = wc * 64 + i * 16 + l15;
    boff[i] = brow * 32 + ((lhi ^ (brow & 3)) * 8);
  }

  f32x4 xr0, xr1, xr2, xr3;  // staging regs (4 ch rows x 4 tok)

#define ALOAD(it)                                                      \
  do {                                                                 \
    xr0 = *(const f32x4*)(xbase + ((it) * 32 + 0) * 1024);             \
    xr1 = *(const f32x4*)(xbase + ((it) * 32 + 1) * 1024);             \
    xr2 = *(const f32x4*)(xbase + ((it) * 32 + 2) * 1024);             \
    xr3 = *(const f32x4*)(xbase + ((it) * 32 + 3) * 1024);             \
  } while (0)

#define AWRITE(bufi)                                                   \
  do {                                                                 \
    _Pragma("unroll") for (int i = 0; i < 4; ++i) {                    \
      uint2 pv;                                                        \
      pv.x = pk2c(xr0[i], xr1[i]);                                     \
      pv.y = pk2c(xr2[i], xr3[i]);                                     \
      *(uint2*)&aB[bufi][aw0 + i * 40] = pv;                           \
    }                                                                  \
  } while (0)

#define BSTAGE(bufi, it)                                               \
  do {                                                                 \
    gload16(bsrc0 + (it) * 32, &bT[bufi][u0 * 8]);                     \
    gload16(bsrc1 + (it) * 32, &bT[bufi][u1 * 8]);                     \
  } while (0)

  f32x4 acc[4][4] = {};

#define QTILE(BUF, IT)                                                        \
  do {                                                                       \
    if ((IT) + 1 < 16) {                                                     \
      ALOAD((IT) + 1);                                                       \
      BSTAGE((BUF) ^ 1, (IT) + 1);                                           \
    }                                                                        \
    bf16x8 af[4], bfr[4];                                                    \
    _Pragma("unroll") for (int mi = 0; mi < 4; ++mi)                          \
        af[mi] = *(const bf16x8*)&aB[BUF][aoff[mi]];                          \
    _Pragma("unroll") for (int ni = 0; ni < 4; ++ni)                          \
        bfr[ni] = *(const bf16x8*)&bT[BUF][boff[ni]];                         \
    __builtin_amdgcn_s_setprio(1);                                           \
    _Pragma("unroll") for (int mi = 0; mi < 4; ++mi)                          \
        _Pragma("unroll") for (int ni = 0; ni < 4; ++ni)                      \
            acc[mi][ni] = MFMA16(af[mi], bfr[ni], acc[mi][ni]);               \
    __builtin_amdgcn_s_setprio(0);                                           \
    if ((IT) + 1 < 16) AWRITE((BUF) ^ 1); /* pack+write after MFMA (T14) */   \
    __syncthreads();                                                         \
  } while (0)

  // prologue: tile 0
  ALOAD(0);
  BSTAGE(0, 0);
  AWRITE(0);
  __syncthreads();
  for (int it2 = 0; it2 < 16; it2 += 2) {
    QTILE(0, it2);
    QTILE(1, it2 + 1);
  }
#undef QTILE
#undef ALOAD
#undef AWRITE
#undef BSTAGE

  float sc = (z == 1) ? (0.125f * 1.44269504f) : 1.0f;
#pragma unroll
  for (int mi = 0; mi < 4; ++mi) {
#pragma unroll
    for (int ni = 0; ni < 4; ++ni) {
      int row = m0 + wr * 64 + mi * 16 + lhi * 4;
      int col = n0 + wc * 64 + ni * 16 + l15;
      if (z < 2) {
        unsigned short* C = z == 0 ? O0 : O1;
#pragma unroll
        for (int j2 = 0; j2 < 4; ++j2)
          C[(size_t)(row + j2) * 512 + col] = f2bf(acc[mi][ni][j2] * sc);
      } else {
        int bb = row >> 10, hw = row & 1023;
        u16x4 p;
        p[0] = f2bf(acc[mi][ni][0]); p[1] = f2bf(acc[mi][ni][1]);
        p[2] = f2bf(acc[mi][ni][2]); p[3] = f2bf(acc[mi][ni][3]);
        *(u16x4*)&O2[(size_t)bb * 524288 + (size_t)col * 1024 + hw] = p;
      }
    }
  }
}

// ---------- final GEMM: x(8192x512)bf16 @ Wo^T -> f32 (b, c, hw) ----------
__global__ __launch_bounds__(256, 4) void gemm_out(const unsigned short* __restrict__ A,
                                                   const unsigned short* __restrict__ BT,
                                                   float* __restrict__ C) {
  __shared__ unsigned short aT[2][128 * 32];
  __shared__ unsigned short bT[2][64 * 32];
  int j = blockIdx.x;
  int bm = (j & 7) * 8 + (j >> 6);
  int bn = (j >> 3) & 7;
  int tid = threadIdx.x, lane = tid & 63, w = tid >> 6;
  int l15 = lane & 15, lhi = lane >> 4;
  const int m0 = bm * 128, n0 = bn * 64;

  int u0 = tid, u1 = 256 + tid;
  int ar0 = u0 >> 2, ac0 = (u0 & 3) ^ (ar0 & 3);
  int ar1 = u1 >> 2, ac1 = (u1 & 3) ^ (ar1 & 3);
  const unsigned short* asrc0 = A + (size_t)(m0 + ar0) * 512 + ac0 * 8;
  const unsigned short* asrc1 = A + (size_t)(m0 + ar1) * 512 + ac1 * 8;
  const unsigned short* bsrc0 = BT + (size_t)(n0 + ar0) * 512 + ac0 * 8;

#define OSTAGE(bufi, it)                                     \
  do {                                                       \
    gload16(asrc0 + (it) * 32, &aT[bufi][u0 * 8]);           \
    gload16(asrc1 + (it) * 32, &aT[bufi][u1 * 8]);           \
    gload16(bsrc0 + (it) * 32, &bT[bufi][u0 * 8]);           \
  } while (0)

  int aoff[2], boff[4];
#pragma unroll
  for (int i = 0; i < 2; ++i) {
    int arow = w * 32 + i * 16 + l15;
    aoff[i] = arow * 32 + ((lhi ^ (arow & 3)) * 8);
  }
#pragma unroll
  for (int i = 0; i < 4; ++i) {
    int brow = i * 16 + l15;
    boff[i] = brow * 32 + ((lhi ^ (brow & 3)) * 8);
  }

  f32x4 acc[2][4] = {};

#define OTILE(BUF, IT)                                                        \
  do {                                                                       \
    if ((IT) + 1 < 16) OSTAGE((BUF) ^ 1, (IT) + 1);                           \
    bf16x8 af[2], bfr[4];                                                    \
    _Pragma("unroll") for (int mi = 0; mi < 2; ++mi)                          \
        af[mi] = *(const bf16x8*)&aT[BUF][aoff[mi]];                          \
    _Pragma("unroll") for (int ni = 0; ni < 4; ++ni)                          \
        bfr[ni] = *(const bf16x8*)&bT[BUF][boff[ni]];                         \
    __builtin_amdgcn_s_setprio(1);                                           \
    _Pragma("unroll") for (int mi = 0; mi < 2; ++mi)                          \
        _Pragma("unroll") for (int ni = 0; ni < 4; ++ni)                      \
            acc[mi][ni] = MFMA16(af[mi], bfr[ni], acc[mi][ni]);               \
    __builtin_amdgcn_s_setprio(0);                                           \
    __syncthreads();                                                         \
  } while (0)

  OSTAGE(0, 0);
  __syncthreads();
  for (int it2 = 0; it2 < 16; it2 += 2) {
    OTILE(0, it2);
    OTILE(1, it2 + 1);
  }
#undef OTILE
#undef OSTAGE

#pragma unroll
  for (int mi = 0; mi < 2; ++mi) {
#pragma unroll
    for (int ni = 0; ni < 4; ++ni) {
      int row = m0 + w * 32 + mi * 16 + lhi * 4;
      int col = n0 + ni * 16 + l15;
      int bb = row >> 10, hw = row & 1023;
      *(f32x4*)&C[(size_t)bb * 524288 + (size_t)col * 1024 + hw] = acc[mi][ni];
    }
  }
}

// ---------- fused flash attention (fixed-shift softmax, swapped QK^T) ----------
// grid 512: xcd-swizzled (bh, qb); 4 waves, QBLK=128 (32 q/wave: 2 subs), KBLK=64
__global__ __launch_bounds__(256, 2) void attn_kernel(
    const unsigned short* __restrict__ q_tok, const unsigned short* __restrict__ k_tok,
    const unsigned short* __restrict__ v_cm, unsigned short* __restrict__ y_hm) {
  __shared__ unsigned short k_lds[2][64 * 64];
  __shared__ unsigned short v_lds[2][64 * 64];
  __shared__ unsigned short p_lds[4][2][16 * 64];

  int bid = blockIdx.x;
  int slot = bid >> 3;
  int bh = (bid & 7) * 8 + (slot >> 3);
  int qb = slot & 7;
  int h = bh & 7, b = bh >> 3;
  int tid = threadIdx.x;
  int lane = tid & 63, w = tid >> 6;
  int l15 = lane & 15, lhi = lane >> 4;

  const unsigned short* kbase = k_tok + (size_t)b * 524288 + h * 64;
  const unsigned short* vbase = v_cm + (size_t)b * 524288 + (size_t)h * 65536;

  int qglob0 = b * 1024 + qb * 128 + w * 32;
  bf16x8 qf[2][2];
#pragma unroll
  for (int sub = 0; sub < 2; ++sub) {
    const unsigned short* qp =
        q_tok + (size_t)(qglob0 + sub * 16 + l15) * 512 + h * 64 + lhi * 8;
    qf[sub][0] = *(const bf16x8*)qp;
    qf[sub][1] = *(const bf16x8*)(qp + 32);
  }

  bf16x8 ones;
#pragma unroll
  for (int i = 0; i < 8; ++i) ones[i] = (__bf16)1.0f;

  int u0 = tid, u1 = 256 + tid;
  int r0 = u0 >> 3, c0 = (u0 & 7) ^ (r0 & 7);
  int r1 = u1 >> 3, c1 = (u1 & 7) ^ (r1 & 7);
  const unsigned short* ksrc0 = kbase + (size_t)r0 * 512 + c0 * 8;
  const unsigned short* ksrc1 = kbase + (size_t)r1 * 512 + c1 * 8;
  const unsigned short* vsrc0 = vbase + (size_t)r0 * 1024 + c0 * 8;
  const unsigned short* vsrc1 = vbase + (size_t)r1 * 1024 + c1 * 8;

#define STAGE(bufi, kti)                                                    \
  do {                                                                      \
    gload16(ksrc0 + (size_t)(kti) * 32768, &k_lds[bufi][u0 * 8]);           \
    gload16(ksrc1 + (size_t)(kti) * 32768, &k_lds[bufi][u1 * 8]);           \
    gload16(vsrc0 + (kti) * 64, &v_lds[bufi][u0 * 8]);                      \
    gload16(vsrc1 + (kti) * 64, &v_lds[bufi][u1 * 8]);                      \
  } while (0)

  int kvoff[4][2];
#pragma unroll
  for (int nt = 0; nt < 4; ++nt) {
    int brow = nt * 16 + l15, sw = brow & 7;
    kvoff[nt][0] = brow * 64 + ((lhi ^ sw) * 8);
    kvoff[nt][1] = brow * 64 + (((4 + lhi) ^ sw) * 8);
  }

  char* pb = (char*)&p_lds[w][0][0];
  int p2 = (l15 & 7) << 1;
  char* pwr[2][4];
  const char* prd[2][2];
#pragma unroll
  for (int sub = 0; sub < 2; ++sub) {
#pragma unroll
    for (int nt = 0; nt < 4; ++nt)
      pwr[sub][nt] = pb + sub * 2048 + l15 * 128 + ((((nt << 2) | lhi) ^ p2) << 3);
#pragma unroll
    for (int kc = 0; kc < 2; ++kc)
      prd[sub][kc] = pb + sub * 2048 + l15 * 128 + ((((kc << 3) | (lhi << 1)) ^ p2) << 3);
  }

  f32x4 ls[2] = {{0.f, 0.f, 0.f, 0.f}, {0.f, 0.f, 0.f, 0.f}};
  f32x4 o[2][4] = {};

#define TILE(BUF, KT)                                                        \
  do {                                                                       \
    if ((KT) + 1 < 16) STAGE((BUF) ^ 1, (KT) + 1);                           \
    const unsigned short* kl = k_lds[BUF];                                   \
    const unsigned short* vl = v_lds[BUF];                                   \
    f32x4 st[2][4];                                                          \
    __builtin_amdgcn_s_setprio(1);                                           \
    _Pragma("unroll") for (int nt = 0; nt < 4; ++nt) {                       \
      bf16x8 kf0 = *(const bf16x8*)&kl[kvoff[nt][0]];                        \
      bf16x8 kf1 = *(const bf16x8*)&kl[kvoff[nt][1]];                        \
      _Pragma("unroll") for (int sub = 0; sub < 2; ++sub) {                  \
        f32x4 a = {0.f, 0.f, 0.f, 0.f};                                      \
        a = MFMA16(kf0, qf[sub][0], a);                                      \
        a = MFMA16(kf1, qf[sub][1], a);                                      \
        st[sub][nt] = a;                                                     \
      }                                                                      \
    }                                                                        \
    __builtin_amdgcn_s_setprio(0);                                           \
    bf16x8 vf[4][2];                                                         \
    _Pragma("unroll") for (int dt = 0; dt < 4; ++dt) {                       \
      vf[dt][0] = *(const bf16x8*)&vl[kvoff[dt][0]];                         \
      vf[dt][1] = *(const bf16x8*)&vl[kvoff[dt][1]];                         \
    }                                                                        \
    _Pragma("unroll") for (int sub = 0; sub < 2; ++sub) {                    \
      _Pragma("unroll") for (int nt = 0; nt < 4; ++nt) {                     \
        float e0 = fexp2(st[sub][nt][0]);                                    \
        float e1 = fexp2(st[sub][nt][1]);                                    \
        float e2 = fexp2(st[sub][nt][2]);                                    \
        float e3 = fexp2(st[sub][nt][3]);                                    \
        uint2 pk;                                                            \
        pk.x = pk2(e0, e1);                                                  \
        pk.y = pk2(e2, e3);                                                  \
        *(uint2*)pwr[sub][nt] = pk;                                          \
      }                                                                      \
    }                                                                        \
    asm volatile("" ::: "memory");                                          \
    bf16x8 pf[2][2];                                                         \
    _Pragma("unroll") for (int sub = 0; sub < 2; ++sub) {                    \
      pf[sub][0] = *(const bf16x8*)prd[sub][0];                              \
      pf[sub][1] = *(const bf16x8*)prd[sub][1];                              \
    }                                                                        \
    __builtin_amdgcn_s_setprio(1);                                           \
    _Pragma("unroll") for (int dt = 0; dt < 4; ++dt) {                       \
      _Pragma("unroll") for (int sub = 0; sub < 2; ++sub) {                  \
        o[sub][dt] = MFMA16(pf[sub][0], vf[dt][0], o[sub][dt]);              \
        o[sub][dt] = MFMA16(pf[sub][1], vf[dt][1], o[sub][dt]);              \
      }                                                                      \
    }                                                                        \
    _Pragma("unroll") for (int sub = 0; sub < 2; ++sub) {                    \
      ls[sub] = MFMA16(pf[sub][0], ones, ls[sub]);                           \
      ls[sub] = MFMA16(pf[sub][1], ones, ls[sub]);                           \
    }                                                                        \
    __builtin_amdgcn_s_setprio(0);                                           \
    __syncthreads();                                                         \
  } while (0)

  STAGE(0, 0);
  __syncthreads();
  for (int kt2 = 0; kt2 < 16; kt2 += 2) {
    TILE(0, kt2);
    TILE(1, kt2 + 1);
  }
#undef TILE
#undef STAGE

#pragma unroll
  for (int sub = 0; sub < 2; ++sub) {
    float inv[4];
#pragma unroll
    for (int r = 0; r < 4; ++r) inv[r] = 1.0f / ls[sub][r];
#pragma unroll
    for (int dt = 0; dt < 4; ++dt) {
#pragma unroll
      for (int r = 0; r < 4; ++r) {
        int q = qglob0 + sub * 16 + lhi * 4 + r;
        size_t idx = (size_t)q * 512 + h * 64 + dt * 16 + l15;
        float res = bf2f(q_tok[idx]);
        y_hm[idx] = f2bf(o[sub][dt][r] * inv[r] + res);
      }
    }
  }
}

// ---------- LayerNorm -> bf16 (with (c m) un-permute at store) ----------
__global__ __launch_bounds__(256) void ln_kernel(
    const unsigned short* __restrict__ y_hm,
    const float* __restrict__ gamma, const float* __restrict__ beta,
    unsigned short* __restrict__ xln) {
  __shared__ float y_s[512];
  __shared__ float red[8];
  int row = blockIdx.x;
  int t = threadIdx.x;
  float y0 = bf2f(y_hm[(size_t)row * 512 + t]);
  float y1 = bf2f(y_hm[(size_t)row * 512 + 256 + t]);
  y_s[t] = y0;
  y_s[t + 256] = y1;
  float s = y0 + y1, ss = y0 * y0 + y1 * y1;
#pragma unroll
  for (int msk = 1; msk < 64; msk <<= 1) {
    s += __shfl_xor(s, msk);
    ss += __shfl_xor(ss, msk);
  }
  int w = t >> 6, lane = t & 63;
  if (lane == 0) { red[w] = s; red[4 + w] = ss; }
  __syncthreads();
  s = (red[0] + red[1]) + (red[2] + red[3]);
  ss = (red[4] + red[5]) + (red[6] + red[7]);
  float mean = s * (1.0f / 512.0f);
  float var = ss * (1.0f / 512.0f) - mean * mean;
  float rstd = rsqrtf(var + 1e-6f);
  int c0 = t, c1 = t + 256;
  int p0 = ((c0 & 7) << 6) | (c0 >> 3);
  int p1 = ((c1 & 7) << 6) | (c1 >> 3);
  xln[(size_t)row * 512 + c0] = f2bf((y_s[p0] - mean) * rstd * gamma[c0] + beta[c0]);
  xln[(size_t)row * 512 + c1] = f2bf((y_s[p1] - mean) * rstd * gamma[c1] + beta[c1]);
}

extern "C" void kernel_launch(void* const* d_in, const int* in_sizes, int n_in,
                              void* d_out, int out_size, void* d_ws, size_t ws_size,
                              hipStream_t stream) {
  const float* key   = (const float*)d_in[0];
  const float* value = (const float*)d_in[1];
  const float* query = (const float*)d_in[2];
  const float* Wq = (const float*)d_in[3];
  const float* Wk = (const float*)d_in[4];
  const float* Wv = (const float*)d_in[5];
  const float* Wo = (const float*)d_in[6];
  const float* gamma = (const float*)d_in[7];
  const float* beta  = (const float*)d_in[8];

  char* ws = (char*)d_ws;
  unsigned short* Wq_b = (unsigned short*)(ws);
  unsigned short* Wk_b = Wq_b + 262144;
  unsigned short* Wv_b = Wk_b + 262144;
  unsigned short* Wo_b = Wv_b + 262144;
  unsigned short* q_tok = (unsigned short*)(ws + (size_t)(26u) * 1048576);
  unsigned short* k_tok = (unsigned short*)(ws + (size_t)(34u) * 1048576);
  unsigned short* v_cm  = (unsigned short*)(ws + (size_t)(42u) * 1048576);
  unsigned short* xln   = (unsigned short*)(ws + (size_t)(2u) * 1048576);
  unsigned short* y_hm  = (unsigned short*)d_out;  // d_out as scratch

  wconv_kernel<<<dim3(128, 4), 256, 0, stream>>>(Wq, Wk, Wv, Wo, Wq_b, Wk_b, Wv_b, Wo_b);
  gemm_qkv<<<dim3(256, 3), 256, 0, stream>>>(query, key, value, Wq_b, Wk_b, Wv_b,
                                             q_tok, k_tok, v_cm);
  attn_kernel<<<512, 256, 0, stream>>>(q_tok, k_tok, v_cm, y_hm);
  ln_kernel<<<8192, 256, 0, stream>>>(y_hm, gamma, beta, xln);
  gemm_out<<<512, 256, 0, stream>>>(xln, Wo_b, (float*)d_out);
}